// Round 1
// baseline (6897.934 us; speedup 1.0000x reference)
//
#include <hip/hip_runtime.h>
#include <math.h>

#define NN 50000
#define EE 800000

// ---------------------------------------------------------------------------
// 16-MAC step: 8 edges (float4 x2 from LDS, broadcast) x 2 output channels.
// ---------------------------------------------------------------------------
__device__ __forceinline__ void gemm16(float h[8][2], const float* sTk, const float* wrow,
                                       int j0, int j1, int eb) {
  float wa = wrow[j0];
  float wb = wrow[j1];
  float4 xa = *(const float4*)(sTk + eb);
  float4 xb = *(const float4*)(sTk + eb + 4);
  h[0][0] += xa.x * wa; h[0][1] += xa.x * wb;
  h[1][0] += xa.y * wa; h[1][1] += xa.y * wb;
  h[2][0] += xa.z * wa; h[2][1] += xa.z * wb;
  h[3][0] += xa.w * wa; h[3][1] += xa.w * wb;
  h[4][0] += xb.x * wa; h[4][1] += xb.x * wb;
  h[5][0] += xb.y * wa; h[5][1] += xb.y * wb;
  h[6][0] += xb.z * wa; h[6][1] += xb.z * wb;
  h[7][0] += xb.w * wa; h[7][1] += xb.w * wb;
}

// ---------------------------------------------------------------------------
// Fold edge-encoder into msg_w1:  Wc[l][c][j] = sum_j' ew[c][j'] * w1[l][256+j'][j]
// and b1f[l][j] = msg_b1[l][j] + sum_j' eb[j'] * w1[l][256+j'][j]
// grid (33, 4): blockIdx.x = c (32 == bias), blockIdx.y = layer. block 128.
// ---------------------------------------------------------------------------
__global__ void fold_kernel(const float* __restrict__ ew, const float* __restrict__ eb,
                            const float* __restrict__ w1, const float* __restrict__ b1,
                            float* __restrict__ Wc, float* __restrict__ b1f) {
  int l = blockIdx.y, c = blockIdx.x, j = threadIdx.x;
  __shared__ float row[128];
  const float* w1l = w1 + (size_t)l * 385 * 128;
  if (c < 32) {
    row[j] = ew[c * 128 + j];
    __syncthreads();
    float acc = 0.f;
    for (int k = 0; k < 128; k++) acc += row[k] * w1l[(256 + k) * 128 + j];
    Wc[((size_t)l * 32 + c) * 128 + j] = acc;
  } else {
    row[j] = eb[j];
    __syncthreads();
    float acc = b1[l * 128 + j];
    for (int k = 0; k < 128; k++) acc += row[k] * w1l[(256 + k) * 128 + j];
    b1f[l * 128 + j] = acc;
  }
}

// ---------------------------------------------------------------------------
// Node encoder: x[n][j] = sum_{k<64} nf[n][k] * wn[k][j] + bn[j]
// block 128 threads = 1 output channel each, 8 nodes per block.
// ---------------------------------------------------------------------------
__global__ void enc_node_kernel(const float* __restrict__ nf, const float* __restrict__ wn,
                                const float* __restrict__ bn, float* __restrict__ x) {
  __shared__ __align__(16) float s[64][8];  // transposed [k][n]
  int t = threadIdx.x;
  long nb = (long)blockIdx.x * 8;
  for (int i = 0; i < 4; i++) {
    int flat = i * 128 + t;
    int n = flat >> 6, k = flat & 63;
    long nn = nb + n;
    s[k][n] = (nn < NN) ? nf[nn * 64 + k] : 0.f;
  }
  __syncthreads();
  float b = bn[t];
  float acc[8];
  for (int n = 0; n < 8; n++) acc[n] = b;
  for (int k = 0; k < 64; k++) {
    float wv = wn[k * 128 + t];
    float4 s0 = *(const float4*)&s[k][0];
    float4 s1 = *(const float4*)&s[k][4];
    acc[0] += s0.x * wv; acc[1] += s0.y * wv; acc[2] += s0.z * wv; acc[3] += s0.w * wv;
    acc[4] += s1.x * wv; acc[5] += s1.y * wv; acc[6] += s1.z * wv; acc[7] += s1.w * wv;
  }
  for (int n = 0; n < 8; n++) {
    long nn = nb + n;
    if (nn < NN) x[nn * 128 + t] = acc[n];
  }
}

// ---------------------------------------------------------------------------
// Message + scatter, one layer. block 256 = 4 waves; 32 edges/block (8/wave);
// each thread owns 2 output channels (lane, lane+64) x its wave's 8 edges.
// h = relu(x[src]@W1a + x[dst]@W1b + ef@Wc + cong*w1[384] + b1f)
// m = h@w2 + b2 ; atomicAdd into agg[dst].
// ---------------------------------------------------------------------------
__global__ __launch_bounds__(256, 4) void msg_kernel(
    const float* __restrict__ x, const float* __restrict__ ef, const float* __restrict__ cong,
    const int* __restrict__ srcv, const int* __restrict__ dstv,
    const float* __restrict__ w1, const float* __restrict__ b1f, const float* __restrict__ Wc,
    const float* __restrict__ w2, const float* __restrict__ b2, float* __restrict__ agg) {
  __shared__ __align__(16) float sT[128][36];  // [k][edge] transposed operand tile
  __shared__ int s_src[32], s_dst[32];
  __shared__ float s_cg[32];

  int t = threadIdx.x, wave = t >> 6, lane = t & 63;
  int j0 = lane, j1 = lane + 64;
  int eb = wave * 8;
  long eb0 = (long)blockIdx.x * 32;

  if (t < 32) {
    int sv = srcv[eb0 + t];
    s_src[t] = sv;
    s_dst[t] = dstv[eb0 + t];
    s_cg[t] = cong[sv];
  }
  __syncthreads();

  float h[8][2];
  {
    float b0 = b1f[j0], bv1 = b1f[j1];
    for (int e = 0; e < 8; e++) { h[e][0] = b0; h[e][1] = bv1; }
  }

  // ---- phase A: x[src] tile, K = 0..127 ----
  for (int i = 0; i < 16; i++) {
    int flat = i * 256 + t;
    int e = flat >> 7, k = flat & 127;
    sT[k][e] = x[(long)s_src[e] * 128 + k];
  }
  __syncthreads();
#pragma unroll 4
  for (int k = 0; k < 128; k++) gemm16(h, &sT[k][0], w1 + k * 128, j0, j1, eb);
  __syncthreads();

  // ---- phase B: x[dst] tile, K = 128..255 ----
  for (int i = 0; i < 16; i++) {
    int flat = i * 256 + t;
    int e = flat >> 7, k = flat & 127;
    sT[k][e] = x[(long)s_dst[e] * 128 + k];
  }
  __syncthreads();
  {
    const float* w1b = w1 + 128 * 128;
#pragma unroll 4
    for (int k = 0; k < 128; k++) gemm16(h, &sT[k][0], w1b + k * 128, j0, j1, eb);
  }
  __syncthreads();

  // ---- phase C: raw edge features through folded weights, K = 32 ----
  for (int i = 0; i < 4; i++) {
    int flat = i * 256 + t;
    int e = flat >> 5, c = flat & 31;
    sT[c][e] = ef[(eb0 + e) * 32 + c];
  }
  __syncthreads();
#pragma unroll 4
  for (int k = 0; k < 32; k++) gemm16(h, &sT[k][0], Wc + k * 128, j0, j1, eb);
  {  // congestion term (m_in[384])
    float wa = w1[384 * 128 + j0], wb = w1[384 * 128 + j1];
    for (int e = 0; e < 8; e++) {
      float cv = s_cg[eb + e];
      h[e][0] += cv * wa;
      h[e][1] += cv * wb;
    }
  }
  __syncthreads();

  // ---- relu + transpose into LDS for second GEMM ----
  for (int e = 0; e < 8; e++) {
    sT[j0][eb + e] = fmaxf(h[e][0], 0.f);
    sT[j1][eb + e] = fmaxf(h[e][1], 0.f);
  }
  __syncthreads();

  float m[8][2];
  {
    float c0 = b2[j0], c1 = b2[j1];
    for (int e = 0; e < 8; e++) { m[e][0] = c0; m[e][1] = c1; }
  }
#pragma unroll 4
  for (int k = 0; k < 128; k++) gemm16(m, &sT[k][0], w2 + k * 128, j0, j1, eb);

  // ---- scatter-add into agg[dst] ----
  for (int e = 0; e < 8; e++) {
    long d = (long)s_dst[eb + e] * 128;
    atomicAdd(&agg[d + j0], m[e][0]);
    atomicAdd(&agg[d + j1], m[e][1]);
  }
}

// ---------------------------------------------------------------------------
// Update + residual + layernorm, one layer (in-place on x).
// block 256 = 4 waves x 8 nodes, same tiling as msg.
// ---------------------------------------------------------------------------
__global__ __launch_bounds__(256, 4) void upd_kernel(
    float* __restrict__ x, const float* __restrict__ agg,
    const float* __restrict__ w1, const float* __restrict__ b1,
    const float* __restrict__ w2, const float* __restrict__ b2,
    const float* __restrict__ g, const float* __restrict__ bb) {
  __shared__ __align__(16) float sT[128][36];
  int t = threadIdx.x, wave = t >> 6, lane = t & 63;
  int j0 = lane, j1 = lane + 64;
  int eb = wave * 8;
  long nb0 = (long)blockIdx.x * 32;

  float h[8][2];
  {
    float b0 = b1[j0], bv1 = b1[j1];
    for (int e = 0; e < 8; e++) { h[e][0] = b0; h[e][1] = bv1; }
  }

  // phase A: x rows
  for (int i = 0; i < 16; i++) {
    int flat = i * 256 + t;
    int e = flat >> 7, k = flat & 127;
    long n = nb0 + e;
    sT[k][e] = (n < NN) ? x[n * 128 + k] : 0.f;
  }
  __syncthreads();
#pragma unroll 4
  for (int k = 0; k < 128; k++) gemm16(h, &sT[k][0], w1 + k * 128, j0, j1, eb);
  __syncthreads();

  // phase B: agg rows
  for (int i = 0; i < 16; i++) {
    int flat = i * 256 + t;
    int e = flat >> 7, k = flat & 127;
    long n = nb0 + e;
    sT[k][e] = (n < NN) ? agg[n * 128 + k] : 0.f;
  }
  __syncthreads();
  {
    const float* w1b = w1 + 128 * 128;
#pragma unroll 4
    for (int k = 0; k < 128; k++) gemm16(h, &sT[k][0], w1b + k * 128, j0, j1, eb);
  }
  __syncthreads();

  // relu + transpose
  for (int e = 0; e < 8; e++) {
    sT[j0][eb + e] = fmaxf(h[e][0], 0.f);
    sT[j1][eb + e] = fmaxf(h[e][1], 0.f);
  }
  __syncthreads();

  float m[8][2];
  {
    float c0 = b2[j0], c1 = b2[j1];
    for (int e = 0; e < 8; e++) { m[e][0] = c0; m[e][1] = c1; }
  }
#pragma unroll 4
  for (int k = 0; k < 128; k++) gemm16(m, &sT[k][0], w2 + k * 128, j0, j1, eb);

  // residual + layernorm (wave-wide reduction over the 128 channels)
  float gw0 = g[j0], gw1 = g[j1], gb0 = bb[j0], gb1 = bb[j1];
  for (int e = 0; e < 8; e++) {
    long n = nb0 + eb + e;  // wave-uniform
    if (n >= NN) continue;
    float y0 = x[n * 128 + j0] + m[e][0];
    float y1 = x[n * 128 + j1] + m[e][1];
    float s = y0 + y1;
    for (int off = 32; off; off >>= 1) s += __shfl_xor(s, off);
    float mu = s * (1.f / 128.f);
    float d0 = y0 - mu, d1 = y1 - mu;
    float q = d0 * d0 + d1 * d1;
    for (int off = 32; off; off >>= 1) q += __shfl_xor(q, off);
    float rstd = rsqrtf(q * (1.f / 128.f) + 1e-5f);
    x[n * 128 + j0] = d0 * rstd * gw0 + gb0;
    x[n * 128 + j1] = d1 * rstd * gw1 + gb1;
  }
}

// ---------------------------------------------------------------------------
// Global reductions: per-channel sum of x, plus unrouted count.
// red[0..127] = channel sums, red[128] = mask sum. grid 256 x 256.
// ---------------------------------------------------------------------------
__global__ void reduce_kernel(const float* __restrict__ x, const int* __restrict__ umask,
                              float* __restrict__ red) {
  int t = threadIdx.x;
  long base = (long)blockIdx.x * 196;
  int j = t & 127, half = t >> 7;
  float acc = 0.f;
  for (int i = 0; i < 98; i++) {
    long n = base + half + 2L * i;
    if (n < NN) acc += x[n * 128 + j];
  }
  __shared__ float sr[2][128];
  __shared__ float sm[4];
  sr[half][j] = acc;
  float mv = 0.f;
  {
    long n = base + t;
    if (t < 196 && n < NN) mv = (float)umask[n];
  }
  for (int off = 32; off; off >>= 1) mv += __shfl_xor(mv, off);
  if ((t & 63) == 0) sm[t >> 6] = mv;
  __syncthreads();
  if (t < 128) atomicAdd(&red[t], sr[0][t] + sr[1][t]);
  if (t == 0) atomicAdd(&red[128], sm[0] + sm[1] + sm[2] + sm[3]);
}

// ---------------------------------------------------------------------------
// Readout head: tiny MLPs -> sigmoid scalar. Single block of 128.
// ---------------------------------------------------------------------------
__global__ void readout_kernel(const float* __restrict__ red,
                               const float* __restrict__ xw1, const float* __restrict__ xb1,
                               const float* __restrict__ xw2, const float* __restrict__ xb2,
                               const float* __restrict__ rw1, const float* __restrict__ rb1,
                               const float* __restrict__ rw2, const float* __restrict__ rb2,
                               const float* __restrict__ rw3, const float* __restrict__ rb3,
                               float* __restrict__ out) {
  __shared__ float sa[128], sb[128], sc[128];
  int j = threadIdx.x;
  const float inv = 1.f / (float)NN;
  float ge = red[j] * inv;
  float uf = red[128] * inv;
  float u1 = fmaxf(uf * xw1[j] + xb1[j], 0.f);
  sa[j] = u1;
  sb[j] = ge;
  __syncthreads();
  float u2 = xb2[j];
  for (int k = 0; k < 128; k++) u2 += sa[k] * xw2[k * 128 + j];
  sc[j] = u2;
  __syncthreads();
  float h1 = rb1[j];
  for (int k = 0; k < 128; k++) h1 += sb[k] * rw1[k * 128 + j];
  for (int k = 0; k < 128; k++) h1 += sc[k] * rw1[(128 + k) * 128 + j];
  h1 = fmaxf(h1, 0.f);
  __syncthreads();
  sa[j] = h1;
  __syncthreads();
  float h2 = 0.f;
  if (j < 64) {
    h2 = rb2[j];
    for (int k = 0; k < 128; k++) h2 += sa[k] * rw2[k * 64 + j];
    h2 = fmaxf(h2, 0.f);
  }
  __syncthreads();
  if (j < 64) sb[j] = h2;
  __syncthreads();
  if (j == 0) {
    float a = rb3[0];
    for (int k = 0; k < 64; k++) a += sb[k] * rw3[k];
    out[0] = 1.f / (1.f + expf(-a));
  }
}

// ---------------------------------------------------------------------------
extern "C" void kernel_launch(void* const* d_in, const int* in_sizes, int n_in,
                              void* d_out, int out_size, void* d_ws, size_t ws_size,
                              hipStream_t stream) {
  const float* nf   = (const float*)d_in[0];
  const float* ef   = (const float*)d_in[1];
  const float* cong = (const float*)d_in[2];
  const int*   eidx = (const int*)d_in[3];
  const int*   um   = (const int*)d_in[4];
  const float* enw  = (const float*)d_in[5];
  const float* enb  = (const float*)d_in[6];
  const float* eew  = (const float*)d_in[7];
  const float* eeb  = (const float*)d_in[8];
  const float* mw1  = (const float*)d_in[9];
  const float* mb1  = (const float*)d_in[10];
  const float* mw2  = (const float*)d_in[11];
  const float* mb2  = (const float*)d_in[12];
  const float* uw1  = (const float*)d_in[13];
  const float* ub1  = (const float*)d_in[14];
  const float* uw2  = (const float*)d_in[15];
  const float* ub2  = (const float*)d_in[16];
  const float* lnw  = (const float*)d_in[17];
  const float* lnb  = (const float*)d_in[18];
  const float* xw1  = (const float*)d_in[19];
  const float* xb1  = (const float*)d_in[20];
  const float* xw2  = (const float*)d_in[21];
  const float* xb2  = (const float*)d_in[22];
  const float* rw1  = (const float*)d_in[23];
  const float* rb1  = (const float*)d_in[24];
  const float* rw2  = (const float*)d_in[25];
  const float* rb2  = (const float*)d_in[26];
  const float* rw3  = (const float*)d_in[27];
  const float* rb3  = (const float*)d_in[28];
  float* out = (float*)d_out;

  float* w   = (float*)d_ws;
  float* x   = w;                    // N*128 = 6.4M floats
  float* agg = w + 6400000;          // N*128
  float* Wc  = w + 12800000;         // 4*32*128
  float* b1f = Wc + 4 * 32 * 128;    // 4*128
  float* red = b1f + 4 * 128;        // 129

  const int* srcv = eidx;
  const int* dstv = eidx + EE;

  fold_kernel<<<dim3(33, 4), 128, 0, stream>>>(eew, eeb, mw1, mb1, Wc, b1f);
  enc_node_kernel<<<6250, 128, 0, stream>>>(nf, enw, enb, x);

  for (int l = 0; l < 4; l++) {
    hipMemsetAsync(agg, 0, (size_t)NN * 128 * sizeof(float), stream);
    msg_kernel<<<25000, 256, 0, stream>>>(
        x, ef, cong, srcv, dstv,
        mw1 + (size_t)l * 385 * 128, b1f + l * 128, Wc + (size_t)l * 32 * 128,
        mw2 + (size_t)l * 128 * 128, mb2 + l * 128, agg);
    upd_kernel<<<1563, 256, 0, stream>>>(
        x, agg,
        uw1 + (size_t)l * 256 * 128, ub1 + l * 128,
        uw2 + (size_t)l * 128 * 128, ub2 + l * 128,
        lnw + l * 128, lnb + l * 128);
  }

  hipMemsetAsync(red, 0, 129 * sizeof(float), stream);
  reduce_kernel<<<256, 256, 0, stream>>>(x, um, red);
  readout_kernel<<<1, 128, 0, stream>>>(red, xw1, xb1, xw2, xb2,
                                        rw1, rb1, rw2, rb2, rw3, rb3, out);
}

// Round 2
// 3176.601 us; speedup vs baseline: 2.1715x; 2.1715x over previous
//
#include <hip/hip_runtime.h>
#include <math.h>

#define NN 50000
#define EE 800000

typedef _Float16 half8 __attribute__((ext_vector_type(8)));
typedef float floatx4 __attribute__((ext_vector_type(4)));

// ---------------------------------------------------------------------------
// Fold edge-encoder into msg_w1:  Wc[l][c][j] = sum_j' ew[c][j'] * w1[l][256+j'][j]
// b1f[l][j] = msg_b1[l][j] + sum_j' eb[j'] * w1[l][256+j'][j]
// grid (33, 4), block 128.
// ---------------------------------------------------------------------------
__global__ void fold_kernel(const float* __restrict__ ew, const float* __restrict__ eb,
                            const float* __restrict__ w1, const float* __restrict__ b1,
                            float* __restrict__ Wc, float* __restrict__ b1f) {
  int l = blockIdx.y, c = blockIdx.x, j = threadIdx.x;
  __shared__ float row[128];
  const float* w1l = w1 + (size_t)l * 385 * 128;
  if (c < 32) {
    row[j] = ew[c * 128 + j];
    __syncthreads();
    float acc = 0.f;
    for (int k = 0; k < 128; k++) acc += row[k] * w1l[(256 + k) * 128 + j];
    Wc[((size_t)l * 32 + c) * 128 + j] = acc;
  } else {
    row[j] = eb[j];
    __syncthreads();
    float acc = b1[l * 128 + j];
    for (int k = 0; k < 128; k++) acc += row[k] * w1l[(256 + k) * 128 + j];
    b1f[l * 128 + j] = acc;
  }
}

// ---------------------------------------------------------------------------
// Pack a [K x 128] fp32 row-major weight matrix into fp16 MFMA B-fragment
// order. Frag block (kc,nt): 64 lanes x 8 halves; element j of lane:
//   W[ ks(kc*32 + (lane>>4)*8 + j) ][ nt*16 + (lane&15) ]
// perm=1 applies the GEMM2 k-permutation col(k') = (k'&7)*16 + (k'>>3)
// (matches the LDS h-tile layout written by the C-layout epilogue).
// grid ((K/32)*8, L), block 64.
// ---------------------------------------------------------------------------
__global__ void prep_w(const float* __restrict__ src, _Float16* __restrict__ dst,
                       int K, int perm) {
  int l = blockIdx.y;
  int lane = threadIdx.x;
  int kc = blockIdx.x >> 3, nt = blockIdx.x & 7;
  int n = nt * 16 + (lane & 15);
  int k0 = kc * 32 + (lane >> 4) * 8;
  const float* s = src + (size_t)l * K * 128;
  _Float16 out[8];
  for (int j = 0; j < 8; j++) {
    int k = k0 + j;
    int ks = perm ? ((k & 7) * 16 + (k >> 3)) : k;
    out[j] = (_Float16)s[(size_t)ks * 128 + n];
  }
  _Float16* d = dst + (((size_t)l * gridDim.x + blockIdx.x) * 64 + lane) * 8;
  *(half8*)d = *(half8*)out;
}

// Composite version for msg W1eff (288 rows: mw1[0..255] ++ Wc[0..31]).
// grid (72, 4), block 64.
__global__ void prep_msg1(const float* __restrict__ mw1, const float* __restrict__ Wc,
                          _Float16* __restrict__ dst) {
  int l = blockIdx.y;
  int lane = threadIdx.x;
  int kc = blockIdx.x >> 3, nt = blockIdx.x & 7;
  int n = nt * 16 + (lane & 15);
  int k0 = kc * 32 + (lane >> 4) * 8;
  _Float16 out[8];
  for (int j = 0; j < 8; j++) {
    int k = k0 + j;
    float v = (k < 256) ? mw1[((size_t)l * 385 + k) * 128 + n]
                        : Wc[((size_t)l * 32 + (k - 256)) * 128 + n];
    out[j] = (_Float16)v;
  }
  _Float16* d = dst + (((size_t)l * 72 + blockIdx.x) * 64 + lane) * 8;
  *(half8*)d = *(half8*)out;
}

// ---------------------------------------------------------------------------
// Node encoder (fp32 VALU; small), now also emits fp16 copy xh.
// ---------------------------------------------------------------------------
__global__ void enc_node_kernel(const float* __restrict__ nf, const float* __restrict__ wn,
                                const float* __restrict__ bn, float* __restrict__ x,
                                _Float16* __restrict__ xh) {
  __shared__ __align__(16) float s[64][8];
  int t = threadIdx.x;
  long nb = (long)blockIdx.x * 8;
  for (int i = 0; i < 4; i++) {
    int flat = i * 128 + t;
    int n = flat >> 6, k = flat & 63;
    long nn = nb + n;
    s[k][n] = (nn < NN) ? nf[nn * 64 + k] : 0.f;
  }
  __syncthreads();
  float b = bn[t];
  float acc[8];
  for (int n = 0; n < 8; n++) acc[n] = b;
  for (int k = 0; k < 64; k++) {
    float wv = wn[k * 128 + t];
    float4 s0 = *(const float4*)&s[k][0];
    float4 s1 = *(const float4*)&s[k][4];
    acc[0] += s0.x * wv; acc[1] += s0.y * wv; acc[2] += s0.z * wv; acc[3] += s0.w * wv;
    acc[4] += s1.x * wv; acc[5] += s1.y * wv; acc[6] += s1.z * wv; acc[7] += s1.w * wv;
  }
  for (int n = 0; n < 8; n++) {
    long nn = nb + n;
    if (nn < NN) {
      x[nn * 128 + t] = acc[n];
      xh[nn * 128 + t] = (_Float16)acc[n];
    }
  }
}

// ---------------------------------------------------------------------------
// Message + scatter (MFMA). block 256 = 4 waves; 32 edges/wave, 128/block.
// GEMM1: A gathered straight from global xh/ef as A-fragments (16B/lane);
// B from pre-packed frags. K = 288 (src 128 | dst 128 | ef 32); congestion
// column + bias fp32 epilogue; relu -> LDS (k-permuted) -> GEMM2 -> atomics.
// ---------------------------------------------------------------------------
__global__ __launch_bounds__(256, 2) void msg_kernel(
    const _Float16* __restrict__ xh, const float* __restrict__ ef,
    const float* __restrict__ cong,
    const int* __restrict__ srcv, const int* __restrict__ dstv,
    const _Float16* __restrict__ Wp1, const _Float16* __restrict__ Wp2,
    const float* __restrict__ wcong, const float* __restrict__ b1f,
    const float* __restrict__ b2, float* __restrict__ agg) {
  __shared__ __align__(16) _Float16 hs[4][32][136];
  __shared__ int s_src[128], s_dst[128];
  __shared__ float s_cg[128];
  int t = threadIdx.x, wave = t >> 6, lane = t & 63;
  int quad = lane >> 4, l15 = lane & 15;
  long eb0 = (long)blockIdx.x * 128;
  if (t < 128) {
    int sv = srcv[eb0 + t];
    s_src[t] = sv;
    s_dst[t] = dstv[eb0 + t];
    s_cg[t] = cong[sv];
  }
  __syncthreads();
  int web = wave * 32;

  floatx4 acc[2][8] = {};
  for (int kc = 0; kc < 9; kc++) {
    half8 a[2];
    if (kc < 8) {
      const int* rows = (kc < 4) ? s_src : s_dst;
      int ko = (kc & 3) * 32 + quad * 8;
      for (int mt = 0; mt < 2; mt++) {
        int r = rows[web + mt * 16 + l15];
        a[mt] = *(const half8*)(xh + (size_t)r * 128 + ko);
      }
    } else {
      for (int mt = 0; mt < 2; mt++) {
        const float* p = ef + (eb0 + web + mt * 16 + l15) * 32 + quad * 8;
        float4 f0 = *(const float4*)p;
        float4 f1 = *(const float4*)(p + 4);
        half8 v;
        v[0] = (_Float16)f0.x; v[1] = (_Float16)f0.y;
        v[2] = (_Float16)f0.z; v[3] = (_Float16)f0.w;
        v[4] = (_Float16)f1.x; v[5] = (_Float16)f1.y;
        v[6] = (_Float16)f1.z; v[7] = (_Float16)f1.w;
        a[mt] = v;
      }
    }
    const _Float16* bp = Wp1 + (size_t)(kc * 8) * 512 + lane * 8;
    for (int nt = 0; nt < 8; nt++) {
      half8 b = *(const half8*)(bp + nt * 512);
      acc[0][nt] = __builtin_amdgcn_mfma_f32_16x16x32_f16(a[0], b, acc[0][nt], 0, 0, 0);
      acc[1][nt] = __builtin_amdgcn_mfma_f32_16x16x32_f16(a[1], b, acc[1][nt], 0, 0, 0);
    }
  }

  // epilogue 1: congestion term + bias, relu, write h-tile (k' = l15*8+nt)
  float wcv[8], bbv[8];
  for (int nt = 0; nt < 8; nt++) {
    int col = nt * 16 + l15;
    wcv[nt] = wcong[col];
    bbv[nt] = b1f[col];
  }
  for (int mt = 0; mt < 2; mt++)
    for (int reg = 0; reg < 4; reg++) {
      int rl = mt * 16 + quad * 4 + reg;
      float cg = s_cg[web + rl];
      half8 hv;
      for (int nt = 0; nt < 8; nt++)
        hv[nt] = (_Float16)fmaxf(acc[mt][nt][reg] + cg * wcv[nt] + bbv[nt], 0.f);
      *(half8*)&hs[wave][rl][l15 * 8] = hv;
    }
  __syncthreads();

  floatx4 acc2[2][8] = {};
  for (int kc = 0; kc < 4; kc++) {
    half8 a[2];
    for (int mt = 0; mt < 2; mt++)
      a[mt] = *(const half8*)&hs[wave][mt * 16 + l15][kc * 32 + quad * 8];
    const _Float16* bp = Wp2 + (size_t)(kc * 8) * 512 + lane * 8;
    for (int nt = 0; nt < 8; nt++) {
      half8 b = *(const half8*)(bp + nt * 512);
      acc2[0][nt] = __builtin_amdgcn_mfma_f32_16x16x32_f16(a[0], b, acc2[0][nt], 0, 0, 0);
      acc2[1][nt] = __builtin_amdgcn_mfma_f32_16x16x32_f16(a[1], b, acc2[1][nt], 0, 0, 0);
    }
  }

  float b2v[8];
  for (int nt = 0; nt < 8; nt++) b2v[nt] = b2[nt * 16 + l15];
  for (int mt = 0; mt < 2; mt++)
    for (int reg = 0; reg < 4; reg++) {
      int el = web + mt * 16 + quad * 4 + reg;
      long dbase = (long)s_dst[el] * 128;
      for (int nt = 0; nt < 8; nt++)
        atomicAdd(&agg[dbase + nt * 16 + l15], acc2[mt][nt][reg] + b2v[nt]);
    }
}

// ---------------------------------------------------------------------------
// Update + residual + layernorm (MFMA). block 256 = 4 waves x 16 nodes.
// ---------------------------------------------------------------------------
__global__ __launch_bounds__(256, 2) void upd_kernel(
    float* __restrict__ x, _Float16* __restrict__ xh, const float* __restrict__ agg,
    const _Float16* __restrict__ Wp1, const _Float16* __restrict__ Wp2,
    const float* __restrict__ b1, const float* __restrict__ b2,
    const float* __restrict__ g, const float* __restrict__ bb) {
  __shared__ __align__(16) _Float16 hs[4][16][136];
  int t = threadIdx.x, wave = t >> 6, lane = t & 63;
  int quad = lane >> 4, l15 = lane & 15;
  long nb0 = (long)blockIdx.x * 64 + wave * 16;

  floatx4 acc[8] = {};
  {
    long n = nb0 + l15;
    long rn = n < NN ? n : NN - 1;
    for (int kc = 0; kc < 8; kc++) {
      half8 a;
      if (kc < 4) {
        a = *(const half8*)(xh + rn * 128 + kc * 32 + quad * 8);
      } else {
        const float* p = agg + rn * 128 + (kc - 4) * 32 + quad * 8;
        float4 f0 = *(const float4*)p;
        float4 f1 = *(const float4*)(p + 4);
        half8 v;
        v[0] = (_Float16)f0.x; v[1] = (_Float16)f0.y;
        v[2] = (_Float16)f0.z; v[3] = (_Float16)f0.w;
        v[4] = (_Float16)f1.x; v[5] = (_Float16)f1.y;
        v[6] = (_Float16)f1.z; v[7] = (_Float16)f1.w;
        a = v;
      }
      const _Float16* bp = Wp1 + (size_t)(kc * 8) * 512 + lane * 8;
      for (int nt = 0; nt < 8; nt++) {
        half8 b = *(const half8*)(bp + nt * 512);
        acc[nt] = __builtin_amdgcn_mfma_f32_16x16x32_f16(a, b, acc[nt], 0, 0, 0);
      }
    }
  }

  float bbv[8];
  for (int nt = 0; nt < 8; nt++) bbv[nt] = b1[nt * 16 + l15];
  for (int reg = 0; reg < 4; reg++) {
    half8 hv;
    for (int nt = 0; nt < 8; nt++)
      hv[nt] = (_Float16)fmaxf(acc[nt][reg] + bbv[nt], 0.f);
    *(half8*)&hs[wave][quad * 4 + reg][l15 * 8] = hv;
  }
  __syncthreads();

  floatx4 acc2[8] = {};
  for (int kc = 0; kc < 4; kc++) {
    half8 a = *(const half8*)&hs[wave][l15][kc * 32 + quad * 8];
    const _Float16* bp = Wp2 + (size_t)(kc * 8) * 512 + lane * 8;
    for (int nt = 0; nt < 8; nt++) {
      half8 b = *(const half8*)(bp + nt * 512);
      acc2[nt] = __builtin_amdgcn_mfma_f32_16x16x32_f16(a, b, acc2[nt], 0, 0, 0);
    }
  }

  // bias + residual + layernorm, C-layout; 16-lane shuffle reductions
  float b2v[8], gv[8], bv[8];
  for (int nt = 0; nt < 8; nt++) {
    int col = nt * 16 + l15;
    b2v[nt] = b2[col]; gv[nt] = g[col]; bv[nt] = bb[col];
  }
  for (int reg = 0; reg < 4; reg++) {
    long n = nb0 + quad * 4 + reg;
    bool ok = n < NN;
    long rn = ok ? n : NN - 1;
    float y[8];
    float s = 0.f;
    for (int nt = 0; nt < 8; nt++) {
      y[nt] = x[rn * 128 + nt * 16 + l15] + acc2[nt][reg] + b2v[nt];
      s += y[nt];
    }
    s += __shfl_xor(s, 1); s += __shfl_xor(s, 2);
    s += __shfl_xor(s, 4); s += __shfl_xor(s, 8);
    float mu = s * (1.f / 128.f);
    float q = 0.f;
    for (int nt = 0; nt < 8; nt++) {
      y[nt] -= mu;
      q += y[nt] * y[nt];
    }
    q += __shfl_xor(q, 1); q += __shfl_xor(q, 2);
    q += __shfl_xor(q, 4); q += __shfl_xor(q, 8);
    float rstd = rsqrtf(q * (1.f / 128.f) + 1e-5f);
    if (ok) {
      for (int nt = 0; nt < 8; nt++) {
        float o = y[nt] * rstd * gv[nt] + bv[nt];
        x[n * 128 + nt * 16 + l15] = o;
        xh[n * 128 + nt * 16 + l15] = (_Float16)o;
      }
    }
  }
}

// ---------------------------------------------------------------------------
// Global reductions: per-channel sum of x + unrouted count.
// ---------------------------------------------------------------------------
__global__ void reduce_kernel(const float* __restrict__ x, const int* __restrict__ umask,
                              float* __restrict__ red) {
  int t = threadIdx.x;
  long base = (long)blockIdx.x * 196;
  int j = t & 127, half = t >> 7;
  float acc = 0.f;
  for (int i = 0; i < 98; i++) {
    long n = base + half + 2L * i;
    if (n < NN) acc += x[n * 128 + j];
  }
  __shared__ float sr[2][128];
  __shared__ float sm[4];
  sr[half][j] = acc;
  float mv = 0.f;
  {
    long n = base + t;
    if (t < 196 && n < NN) mv = (float)umask[n];
  }
  for (int off = 32; off; off >>= 1) mv += __shfl_xor(mv, off);
  if ((t & 63) == 0) sm[t >> 6] = mv;
  __syncthreads();
  if (t < 128) atomicAdd(&red[t], sr[0][t] + sr[1][t]);
  if (t == 0) atomicAdd(&red[128], sm[0] + sm[1] + sm[2] + sm[3]);
}

// ---------------------------------------------------------------------------
// Readout head.
// ---------------------------------------------------------------------------
__global__ void readout_kernel(const float* __restrict__ red,
                               const float* __restrict__ xw1, const float* __restrict__ xb1,
                               const float* __restrict__ xw2, const float* __restrict__ xb2,
                               const float* __restrict__ rw1, const float* __restrict__ rb1,
                               const float* __restrict__ rw2, const float* __restrict__ rb2,
                               const float* __restrict__ rw3, const float* __restrict__ rb3,
                               float* __restrict__ out) {
  __shared__ float sa[128], sb[128], sc[128];
  int j = threadIdx.x;
  const float inv = 1.f / (float)NN;
  float ge = red[j] * inv;
  float uf = red[128] * inv;
  float u1 = fmaxf(uf * xw1[j] + xb1[j], 0.f);
  sa[j] = u1;
  sb[j] = ge;
  __syncthreads();
  float u2 = xb2[j];
  for (int k = 0; k < 128; k++) u2 += sa[k] * xw2[k * 128 + j];
  sc[j] = u2;
  __syncthreads();
  float h1 = rb1[j];
  for (int k = 0; k < 128; k++) h1 += sb[k] * rw1[k * 128 + j];
  for (int k = 0; k < 128; k++) h1 += sc[k] * rw1[(128 + k) * 128 + j];
  h1 = fmaxf(h1, 0.f);
  __syncthreads();
  sa[j] = h1;
  __syncthreads();
  float h2 = 0.f;
  if (j < 64) {
    h2 = rb2[j];
    for (int k = 0; k < 128; k++) h2 += sa[k] * rw2[k * 64 + j];
    h2 = fmaxf(h2, 0.f);
  }
  __syncthreads();
  if (j < 64) sb[j] = h2;
  __syncthreads();
  if (j == 0) {
    float a = rb3[0];
    for (int k = 0; k < 64; k++) a += sb[k] * rw3[k];
    out[0] = 1.f / (1.f + expf(-a));
  }
}

// ---------------------------------------------------------------------------
extern "C" void kernel_launch(void* const* d_in, const int* in_sizes, int n_in,
                              void* d_out, int out_size, void* d_ws, size_t ws_size,
                              hipStream_t stream) {
  const float* nf   = (const float*)d_in[0];
  const float* ef   = (const float*)d_in[1];
  const float* cong = (const float*)d_in[2];
  const int*   eidx = (const int*)d_in[3];
  const int*   um   = (const int*)d_in[4];
  const float* enw  = (const float*)d_in[5];
  const float* enb  = (const float*)d_in[6];
  const float* eew  = (const float*)d_in[7];
  const float* eeb  = (const float*)d_in[8];
  const float* mw1  = (const float*)d_in[9];
  const float* mb1  = (const float*)d_in[10];
  const float* mw2  = (const float*)d_in[11];
  const float* mb2  = (const float*)d_in[12];
  const float* uw1  = (const float*)d_in[13];
  const float* ub1  = (const float*)d_in[14];
  const float* uw2  = (const float*)d_in[15];
  const float* ub2  = (const float*)d_in[16];
  const float* lnw  = (const float*)d_in[17];
  const float* lnb  = (const float*)d_in[18];
  const float* xw1  = (const float*)d_in[19];
  const float* xb1  = (const float*)d_in[20];
  const float* xw2  = (const float*)d_in[21];
  const float* xb2  = (const float*)d_in[22];
  const float* rw1  = (const float*)d_in[23];
  const float* rb1  = (const float*)d_in[24];
  const float* rw2  = (const float*)d_in[25];
  const float* rb2  = (const float*)d_in[26];
  const float* rw3  = (const float*)d_in[27];
  const float* rb3  = (const float*)d_in[28];
  float* out = (float*)d_out;

  char* W = (char*)d_ws;
  float*    x    = (float*)(W + 0);            // 25,600,000 B
  float*    agg  = (float*)(W + 25600000);     // 25,600,000 B
  _Float16* xh   = (_Float16*)(W + 51200000);  // 12,800,000 B
  _Float16* Wm1  = (_Float16*)(W + 64000000);  // 294,912 B (4 x 72 frag-blocks)
  _Float16* Wm2  = (_Float16*)(W + 64294912);  // 131,072 B (4 x 32)
  _Float16* Wu1  = (_Float16*)(W + 64425984);  // 262,144 B (4 x 64)
  _Float16* Wu2  = (_Float16*)(W + 64688128);  // 131,072 B (4 x 32)
  float*    Wc   = (float*)(W + 64819200);     // 65,536 B
  float*    b1f  = (float*)(W + 64884736);     // 2,048 B
  float*    red  = (float*)(W + 64886784);     // 516 B

  const int* srcv = eidx;
  const int* dstv = eidx + EE;

  fold_kernel<<<dim3(33, 4), 128, 0, stream>>>(eew, eeb, mw1, mb1, Wc, b1f);
  prep_msg1<<<dim3(72, 4), 64, 0, stream>>>(mw1, Wc, Wm1);
  prep_w<<<dim3(32, 4), 64, 0, stream>>>(mw2, Wm2, 128, 1);
  prep_w<<<dim3(64, 4), 64, 0, stream>>>(uw1, Wu1, 256, 0);
  prep_w<<<dim3(32, 4), 64, 0, stream>>>(uw2, Wu2, 128, 1);
  enc_node_kernel<<<6250, 128, 0, stream>>>(nf, enw, enb, x, xh);

  for (int l = 0; l < 4; l++) {
    hipMemsetAsync(agg, 0, (size_t)NN * 128 * sizeof(float), stream);
    msg_kernel<<<6250, 256, 0, stream>>>(
        xh, ef, cong, srcv, dstv,
        Wm1 + (size_t)l * 72 * 512, Wm2 + (size_t)l * 32 * 512,
        mw1 + (size_t)l * 385 * 128 + (size_t)384 * 128,
        b1f + l * 128, mb2 + l * 128, agg);
    upd_kernel<<<782, 256, 0, stream>>>(
        x, xh, agg,
        Wu1 + (size_t)l * 64 * 512, Wu2 + (size_t)l * 32 * 512,
        ub1 + l * 128, ub2 + l * 128, lnw + l * 128, lnb + l * 128);
  }

  hipMemsetAsync(red, 0, 129 * sizeof(float), stream);
  reduce_kernel<<<256, 256, 0, stream>>>(x, um, red);
  readout_kernel<<<1, 128, 0, stream>>>(red, xw1, xb1, xw2, xb2,
                                        rw1, rb1, rw2, rb2, rw3, rb3, out);
}

// Round 4
// 2072.014 us; speedup vs baseline: 3.3291x; 1.5331x over previous
//
#include <hip/hip_runtime.h>
#include <hip/hip_fp16.h>
#include <math.h>

#define NN 50000
#define EE 800000

typedef _Float16 half8 __attribute__((ext_vector_type(8)));
typedef float floatx4 __attribute__((ext_vector_type(4)));

// ---------------------------------------------------------------------------
// Fold edge-encoder into msg_w1:  Wc[l][c][j] = sum_j' ew[c][j'] * w1[l][256+j'][j]
// b1f[l][j] = msg_b1[l][j] + sum_j' eb[j'] * w1[l][256+j'][j]
// grid (33, 4), block 128.
// ---------------------------------------------------------------------------
__global__ void fold_kernel(const float* __restrict__ ew, const float* __restrict__ eb,
                            const float* __restrict__ w1, const float* __restrict__ b1,
                            float* __restrict__ Wc, float* __restrict__ b1f) {
  int l = blockIdx.y, c = blockIdx.x, j = threadIdx.x;
  __shared__ float row[128];
  const float* w1l = w1 + (size_t)l * 385 * 128;
  if (c < 32) {
    row[j] = ew[c * 128 + j];
    __syncthreads();
    float acc = 0.f;
    for (int k = 0; k < 128; k++) acc += row[k] * w1l[(256 + k) * 128 + j];
    Wc[((size_t)l * 32 + c) * 128 + j] = acc;
  } else {
    row[j] = eb[j];
    __syncthreads();
    float acc = b1[l * 128 + j];
    for (int k = 0; k < 128; k++) acc += row[k] * w1l[(256 + k) * 128 + j];
    b1f[l * 128 + j] = acc;
  }
}

// ---------------------------------------------------------------------------
// Pack a [K x 128] fp32 row-major weight matrix into fp16 MFMA B-fragment
// order. Frag block (kc,nt): 64 lanes x 8 halves; element j of lane:
//   W[ ks(kc*32 + (lane>>4)*8 + j) ][ nt*16 + (lane&15) ]
// perm=1 applies the GEMM2 k-permutation col(k') = (k'&7)*16 + (k'>>3).
// grid ((K/32)*8, L), block 64.
// ---------------------------------------------------------------------------
__global__ void prep_w(const float* __restrict__ src, _Float16* __restrict__ dst,
                       int K, int perm) {
  int l = blockIdx.y;
  int lane = threadIdx.x;
  int kc = blockIdx.x >> 3, nt = blockIdx.x & 7;
  int n = nt * 16 + (lane & 15);
  int k0 = kc * 32 + (lane >> 4) * 8;
  const float* s = src + (size_t)l * K * 128;
  _Float16 out[8];
  for (int j = 0; j < 8; j++) {
    int k = k0 + j;
    int ks = perm ? ((k & 7) * 16 + (k >> 3)) : k;
    out[j] = (_Float16)s[(size_t)ks * 128 + n];
  }
  _Float16* d = dst + (((size_t)l * gridDim.x + blockIdx.x) * 64 + lane) * 8;
  *(half8*)d = *(half8*)out;
}

// Composite version for msg W1eff (288 rows: mw1[0..255] ++ Wc[0..31]).
// grid (72, 4), block 64.
__global__ void prep_msg1(const float* __restrict__ mw1, const float* __restrict__ Wc,
                          _Float16* __restrict__ dst) {
  int l = blockIdx.y;
  int lane = threadIdx.x;
  int kc = blockIdx.x >> 3, nt = blockIdx.x & 7;
  int n = nt * 16 + (lane & 15);
  int k0 = kc * 32 + (lane >> 4) * 8;
  _Float16 out[8];
  for (int j = 0; j < 8; j++) {
    int k = k0 + j;
    float v = (k < 256) ? mw1[((size_t)l * 385 + k) * 128 + n]
                        : Wc[((size_t)l * 32 + (k - 256)) * 128 + n];
    out[j] = (_Float16)v;
  }
  _Float16* d = dst + (((size_t)l * 72 + blockIdx.x) * 64 + lane) * 8;
  *(half8*)d = *(half8*)out;
}

// ---------------------------------------------------------------------------
// Node encoder via MFMA: x0 = nf @ Wn + bn. block 256 = 4 waves x 16 nodes.
// ---------------------------------------------------------------------------
__global__ void enc_mfma(const float* __restrict__ nf, const _Float16* __restrict__ Wenc,
                         const float* __restrict__ bn, float* __restrict__ x,
                         _Float16* __restrict__ xh) {
  int t = threadIdx.x, wave = t >> 6, lane = t & 63;
  int quad = lane >> 4, l15 = lane & 15;
  long nb0 = (long)blockIdx.x * 64 + wave * 16;
  long rn = nb0 + l15;
  if (rn >= NN) rn = NN - 1;

  floatx4 acc[8] = {};
  for (int kc = 0; kc < 2; kc++) {
    const float* p = nf + rn * 64 + kc * 32 + quad * 8;
    float4 f0 = *(const float4*)p;
    float4 f1 = *(const float4*)(p + 4);
    half8 a;
    a[0] = (_Float16)f0.x; a[1] = (_Float16)f0.y;
    a[2] = (_Float16)f0.z; a[3] = (_Float16)f0.w;
    a[4] = (_Float16)f1.x; a[5] = (_Float16)f1.y;
    a[6] = (_Float16)f1.z; a[7] = (_Float16)f1.w;
    const _Float16* bp = Wenc + (size_t)(kc * 8) * 512 + lane * 8;
    for (int nt = 0; nt < 8; nt++) {
      half8 b = *(const half8*)(bp + nt * 512);
      acc[nt] = __builtin_amdgcn_mfma_f32_16x16x32_f16(a, b, acc[nt], 0, 0, 0);
    }
  }
  float bv[8];
  for (int nt = 0; nt < 8; nt++) bv[nt] = bn[nt * 16 + l15];
  for (int reg = 0; reg < 4; reg++) {
    long n = nb0 + quad * 4 + reg;
    if (n < NN) {
      for (int nt = 0; nt < 8; nt++) {
        int col = nt * 16 + l15;
        float v = acc[nt][reg] + bv[nt];
        x[n * 128 + col] = v;
        xh[n * 128 + col] = (_Float16)v;
      }
    }
  }
}

// ---------------------------------------------------------------------------
// Message + scatter (MFMA). block 256 = 4 waves; 32 edges/wave, 128/block.
// GEMM1: A gathered straight from global xh/ef as A-fragments (16B/lane);
// B from pre-packed frags. K = 288 (src 128 | dst 128 | ef 32); congestion
// column + bias fp32 epilogue; relu -> LDS (k-permuted) -> GEMM2 ->
// packed-fp16 atomics into agg (global_atomic_pk_add_f16 via unsafeAtomicAdd).
// ---------------------------------------------------------------------------
__global__ __launch_bounds__(256, 2) void msg_kernel(
    const _Float16* __restrict__ xh, const float* __restrict__ ef,
    const float* __restrict__ cong,
    const int* __restrict__ srcv, const int* __restrict__ dstv,
    const _Float16* __restrict__ Wp1, const _Float16* __restrict__ Wp2,
    const float* __restrict__ wcong, const float* __restrict__ b1f,
    const float* __restrict__ b2, __half* __restrict__ agg) {
  __shared__ __align__(16) _Float16 hs[4][32][136];
  __shared__ int s_src[128], s_dst[128];
  __shared__ float s_cg[128];
  int t = threadIdx.x, wave = t >> 6, lane = t & 63;
  int quad = lane >> 4, l15 = lane & 15;
  long eb0 = (long)blockIdx.x * 128;
  if (t < 128) {
    int sv = srcv[eb0 + t];
    s_src[t] = sv;
    s_dst[t] = dstv[eb0 + t];
    s_cg[t] = cong[sv];
  }
  __syncthreads();
  int web = wave * 32;

  floatx4 acc[2][8] = {};
  for (int kc = 0; kc < 9; kc++) {
    half8 a[2];
    if (kc < 8) {
      const int* rows = (kc < 4) ? s_src : s_dst;
      int ko = (kc & 3) * 32 + quad * 8;
      for (int mt = 0; mt < 2; mt++) {
        int r = rows[web + mt * 16 + l15];
        a[mt] = *(const half8*)(xh + (size_t)r * 128 + ko);
      }
    } else {
      for (int mt = 0; mt < 2; mt++) {
        const float* p = ef + (eb0 + web + mt * 16 + l15) * 32 + quad * 8;
        float4 f0 = *(const float4*)p;
        float4 f1 = *(const float4*)(p + 4);
        half8 v;
        v[0] = (_Float16)f0.x; v[1] = (_Float16)f0.y;
        v[2] = (_Float16)f0.z; v[3] = (_Float16)f0.w;
        v[4] = (_Float16)f1.x; v[5] = (_Float16)f1.y;
        v[6] = (_Float16)f1.z; v[7] = (_Float16)f1.w;
        a[mt] = v;
      }
    }
    const _Float16* bp = Wp1 + (size_t)(kc * 8) * 512 + lane * 8;
    for (int nt = 0; nt < 8; nt++) {
      half8 b = *(const half8*)(bp + nt * 512);
      acc[0][nt] = __builtin_amdgcn_mfma_f32_16x16x32_f16(a[0], b, acc[0][nt], 0, 0, 0);
      acc[1][nt] = __builtin_amdgcn_mfma_f32_16x16x32_f16(a[1], b, acc[1][nt], 0, 0, 0);
    }
  }

  // epilogue 1: congestion term + bias, relu, write h-tile (k' = l15*8+nt)
  float wcv[8], bbv[8];
  for (int nt = 0; nt < 8; nt++) {
    int col = nt * 16 + l15;
    wcv[nt] = wcong[col];
    bbv[nt] = b1f[col];
  }
  for (int mt = 0; mt < 2; mt++)
    for (int reg = 0; reg < 4; reg++) {
      int rl = mt * 16 + quad * 4 + reg;
      float cg = s_cg[web + rl];
      half8 hv;
      for (int nt = 0; nt < 8; nt++)
        hv[nt] = (_Float16)fmaxf(acc[mt][nt][reg] + cg * wcv[nt] + bbv[nt], 0.f);
      *(half8*)&hs[wave][rl][l15 * 8] = hv;
    }
  __syncthreads();

  floatx4 acc2[2][8] = {};
  for (int kc = 0; kc < 4; kc++) {
    half8 a[2];
    for (int mt = 0; mt < 2; mt++)
      a[mt] = *(const half8*)&hs[wave][mt * 16 + l15][kc * 32 + quad * 8];
    const _Float16* bp = Wp2 + (size_t)(kc * 8) * 512 + lane * 8;
    for (int nt = 0; nt < 8; nt++) {
      half8 b = *(const half8*)(bp + nt * 512);
      acc2[0][nt] = __builtin_amdgcn_mfma_f32_16x16x32_f16(a[0], b, acc2[0][nt], 0, 0, 0);
      acc2[1][nt] = __builtin_amdgcn_mfma_f32_16x16x32_f16(a[1], b, acc2[1][nt], 0, 0, 0);
    }
  }

  // packed fp16 atomic scatter: pair columns (2c,2c+1) via lane^1 shuffle,
  // even l15 lanes issue one packed-fp16 atomic for both.
  float b2v[8];
  for (int nt = 0; nt < 8; nt++) b2v[nt] = b2[nt * 16 + l15];
  for (int mt = 0; mt < 2; mt++)
    for (int reg = 0; reg < 4; reg++) {
      int el = web + mt * 16 + quad * 4 + reg;
      long dbase = (long)s_dst[el] * 128;
      for (int nt = 0; nt < 8; nt++) {
        float v = acc2[mt][nt][reg] + b2v[nt];
        float p = __shfl_xor(v, 1);
        if ((l15 & 1) == 0) {
          unsafeAtomicAdd((__half2*)(agg + dbase + nt * 16 + l15),
                          __halves2half2(__float2half(v), __float2half(p)));
        }
      }
    }
}

// ---------------------------------------------------------------------------
// Update + residual + layernorm (MFMA). block 256 = 4 waves x 16 nodes.
// agg now fp16 -> direct A-fragment loads.
// ---------------------------------------------------------------------------
__global__ __launch_bounds__(256, 2) void upd_kernel(
    float* __restrict__ x, _Float16* __restrict__ xh, const _Float16* __restrict__ agg,
    const _Float16* __restrict__ Wp1, const _Float16* __restrict__ Wp2,
    const float* __restrict__ b1, const float* __restrict__ b2,
    const float* __restrict__ g, const float* __restrict__ bb) {
  __shared__ __align__(16) _Float16 hs[4][16][136];
  int t = threadIdx.x, wave = t >> 6, lane = t & 63;
  int quad = lane >> 4, l15 = lane & 15;
  long nb0 = (long)blockIdx.x * 64 + wave * 16;

  floatx4 acc[8] = {};
  {
    long n = nb0 + l15;
    long rn = n < NN ? n : NN - 1;
    for (int kc = 0; kc < 8; kc++) {
      half8 a;
      if (kc < 4) {
        a = *(const half8*)(xh + rn * 128 + kc * 32 + quad * 8);
      } else {
        a = *(const half8*)(agg + rn * 128 + (kc - 4) * 32 + quad * 8);
      }
      const _Float16* bp = Wp1 + (size_t)(kc * 8) * 512 + lane * 8;
      for (int nt = 0; nt < 8; nt++) {
        half8 b = *(const half8*)(bp + nt * 512);
        acc[nt] = __builtin_amdgcn_mfma_f32_16x16x32_f16(a, b, acc[nt], 0, 0, 0);
      }
    }
  }

  float bbv[8];
  for (int nt = 0; nt < 8; nt++) bbv[nt] = b1[nt * 16 + l15];
  for (int reg = 0; reg < 4; reg++) {
    half8 hv;
    for (int nt = 0; nt < 8; nt++)
      hv[nt] = (_Float16)fmaxf(acc[nt][reg] + bbv[nt], 0.f);
    *(half8*)&hs[wave][quad * 4 + reg][l15 * 8] = hv;
  }
  __syncthreads();

  floatx4 acc2[8] = {};
  for (int kc = 0; kc < 4; kc++) {
    half8 a = *(const half8*)&hs[wave][l15][kc * 32 + quad * 8];
    const _Float16* bp = Wp2 + (size_t)(kc * 8) * 512 + lane * 8;
    for (int nt = 0; nt < 8; nt++) {
      half8 b = *(const half8*)(bp + nt * 512);
      acc2[nt] = __builtin_amdgcn_mfma_f32_16x16x32_f16(a, b, acc2[nt], 0, 0, 0);
    }
  }

  // bias + residual + layernorm, C-layout; 16-lane shuffle reductions
  float b2v[8], gv[8], bv[8];
  for (int nt = 0; nt < 8; nt++) {
    int col = nt * 16 + l15;
    b2v[nt] = b2[col]; gv[nt] = g[col]; bv[nt] = bb[col];
  }
  for (int reg = 0; reg < 4; reg++) {
    long n = nb0 + quad * 4 + reg;
    bool ok = n < NN;
    long rn = ok ? n : NN - 1;
    float y[8];
    float s = 0.f;
    for (int nt = 0; nt < 8; nt++) {
      y[nt] = x[rn * 128 + nt * 16 + l15] + acc2[nt][reg] + b2v[nt];
      s += y[nt];
    }
    s += __shfl_xor(s, 1); s += __shfl_xor(s, 2);
    s += __shfl_xor(s, 4); s += __shfl_xor(s, 8);
    float mu = s * (1.f / 128.f);
    float q = 0.f;
    for (int nt = 0; nt < 8; nt++) {
      y[nt] -= mu;
      q += y[nt] * y[nt];
    }
    q += __shfl_xor(q, 1); q += __shfl_xor(q, 2);
    q += __shfl_xor(q, 4); q += __shfl_xor(q, 8);
    float rstd = rsqrtf(q * (1.f / 128.f) + 1e-5f);
    if (ok) {
      for (int nt = 0; nt < 8; nt++) {
        float o = y[nt] * rstd * gv[nt] + bv[nt];
        x[n * 128 + nt * 16 + l15] = o;
        xh[n * 128 + nt * 16 + l15] = (_Float16)o;
      }
    }
  }
}

// ---------------------------------------------------------------------------
// Global reductions: per-channel sum of x + unrouted count.
// ---------------------------------------------------------------------------
__global__ void reduce_kernel(const float* __restrict__ x, const int* __restrict__ umask,
                              float* __restrict__ red) {
  int t = threadIdx.x;
  long base = (long)blockIdx.x * 196;
  int j = t & 127, half = t >> 7;
  float acc = 0.f;
  for (int i = 0; i < 98; i++) {
    long n = base + half + 2L * i;
    if (n < NN) acc += x[n * 128 + j];
  }
  __shared__ float sr[2][128];
  __shared__ float sm[4];
  sr[half][j] = acc;
  float mv = 0.f;
  {
    long n = base + t;
    if (t < 196 && n < NN) mv = (float)umask[n];
  }
  for (int off = 32; off; off >>= 1) mv += __shfl_xor(mv, off);
  if ((t & 63) == 0) sm[t >> 6] = mv;
  __syncthreads();
  if (t < 128) atomicAdd(&red[t], sr[0][t] + sr[1][t]);
  if (t == 0) atomicAdd(&red[128], sm[0] + sm[1] + sm[2] + sm[3]);
}

// ---------------------------------------------------------------------------
// Readout head.
// ---------------------------------------------------------------------------
__global__ void readout_kernel(const float* __restrict__ red,
                               const float* __restrict__ xw1, const float* __restrict__ xb1,
                               const float* __restrict__ xw2, const float* __restrict__ xb2,
                               const float* __restrict__ rw1, const float* __restrict__ rb1,
                               const float* __restrict__ rw2, const float* __restrict__ rb2,
                               const float* __restrict__ rw3, const float* __restrict__ rb3,
                               float* __restrict__ out) {
  __shared__ float sa[128], sb[128], sc[128];
  int j = threadIdx.x;
  const float inv = 1.f / (float)NN;
  float ge = red[j] * inv;
  float uf = red[128] * inv;
  float u1 = fmaxf(uf * xw1[j] + xb1[j], 0.f);
  sa[j] = u1;
  sb[j] = ge;
  __syncthreads();
  float u2 = xb2[j];
  for (int k = 0; k < 128; k++) u2 += sa[k] * xw2[k * 128 + j];
  sc[j] = u2;
  __syncthreads();
  float h1 = rb1[j];
  for (int k = 0; k < 128; k++) h1 += sb[k] * rw1[k * 128 + j];
  for (int k = 0; k < 128; k++) h1 += sc[k] * rw1[(128 + k) * 128 + j];
  h1 = fmaxf(h1, 0.f);
  __syncthreads();
  sa[j] = h1;
  __syncthreads();
  float h2 = 0.f;
  if (j < 64) {
    h2 = rb2[j];
    for (int k = 0; k < 128; k++) h2 += sa[k] * rw2[k * 64 + j];
    h2 = fmaxf(h2, 0.f);
  }
  __syncthreads();
  if (j < 64) sb[j] = h2;
  __syncthreads();
  if (j == 0) {
    float a = rb3[0];
    for (int k = 0; k < 64; k++) a += sb[k] * rw3[k];
    out[0] = 1.f / (1.f + expf(-a));
  }
}

// ---------------------------------------------------------------------------
extern "C" void kernel_launch(void* const* d_in, const int* in_sizes, int n_in,
                              void* d_out, int out_size, void* d_ws, size_t ws_size,
                              hipStream_t stream) {
  const float* nf   = (const float*)d_in[0];
  const float* ef   = (const float*)d_in[1];
  const float* cong = (const float*)d_in[2];
  const int*   eidx = (const int*)d_in[3];
  const int*   um   = (const int*)d_in[4];
  const float* enw  = (const float*)d_in[5];
  const float* enb  = (const float*)d_in[6];
  const float* eew  = (const float*)d_in[7];
  const float* eeb  = (const float*)d_in[8];
  const float* mw1  = (const float*)d_in[9];
  const float* mb1  = (const float*)d_in[10];
  const float* mw2  = (const float*)d_in[11];
  const float* mb2  = (const float*)d_in[12];
  const float* uw1  = (const float*)d_in[13];
  const float* ub1  = (const float*)d_in[14];
  const float* uw2  = (const float*)d_in[15];
  const float* ub2  = (const float*)d_in[16];
  const float* lnw  = (const float*)d_in[17];
  const float* lnb  = (const float*)d_in[18];
  const float* xw1  = (const float*)d_in[19];
  const float* xb1  = (const float*)d_in[20];
  const float* xw2  = (const float*)d_in[21];
  const float* xb2  = (const float*)d_in[22];
  const float* rw1  = (const float*)d_in[23];
  const float* rb1  = (const float*)d_in[24];
  const float* rw2  = (const float*)d_in[25];
  const float* rb2  = (const float*)d_in[26];
  const float* rw3  = (const float*)d_in[27];
  const float* rb3  = (const float*)d_in[28];
  float* out = (float*)d_out;

  char* W = (char*)d_ws;
  float*    x    = (float*)(W + 0);            // 25,600,000 B
  __half*   agg  = (__half*)(W + 25600000);    // 12,800,000 B (fp16 now)
  _Float16* xh   = (_Float16*)(W + 38400000);  // 12,800,000 B
  _Float16* Wm1  = (_Float16*)(W + 51200000);  // 294,912 B
  _Float16* Wm2  = (_Float16*)(W + 51494912);  // 131,072 B
  _Float16* Wu1  = (_Float16*)(W + 51625984);  // 262,144 B
  _Float16* Wu2  = (_Float16*)(W + 51888128);  // 131,072 B
  _Float16* Wen  = (_Float16*)(W + 52019200);  // 16,384 B
  float*    Wc   = (float*)(W + 52035584);     // 65,536 B
  float*    b1f  = (float*)(W + 52101120);     // 2,048 B
  float*    red  = (float*)(W + 52103168);     // 516 B

  const int* srcv = eidx;
  const int* dstv = eidx + EE;

  fold_kernel<<<dim3(33, 4), 128, 0, stream>>>(eew, eeb, mw1, mb1, Wc, b1f);
  prep_msg1<<<dim3(72, 4), 64, 0, stream>>>(mw1, Wc, Wm1);
  prep_w<<<dim3(32, 4), 64, 0, stream>>>(mw2, Wm2, 128, 1);
  prep_w<<<dim3(64, 4), 64, 0, stream>>>(uw1, Wu1, 256, 0);
  prep_w<<<dim3(32, 4), 64, 0, stream>>>(uw2, Wu2, 128, 1);
  prep_w<<<dim3(16, 1), 64, 0, stream>>>(enw, Wen, 64, 0);
  enc_mfma<<<782, 256, 0, stream>>>(nf, Wen, enb, x, xh);

  for (int l = 0; l < 4; l++) {
    (void)hipMemsetAsync(agg, 0, (size_t)NN * 128 * sizeof(__half), stream);
    msg_kernel<<<6250, 256, 0, stream>>>(
        xh, ef, cong, srcv, dstv,
        Wm1 + (size_t)l * 72 * 512, Wm2 + (size_t)l * 32 * 512,
        mw1 + (size_t)l * 385 * 128 + (size_t)384 * 128,
        b1f + l * 128, mb2 + l * 128, agg);
    upd_kernel<<<782, 256, 0, stream>>>(
        x, xh, (const _Float16*)agg,
        Wu1 + (size_t)l * 64 * 512, Wu2 + (size_t)l * 32 * 512,
        ub1 + l * 128, ub2 + l * 128, lnw + l * 128, lnb + l * 128);
  }

  (void)hipMemsetAsync(red, 0, 129 * sizeof(float), stream);
  reduce_kernel<<<256, 256, 0, stream>>>(x, um, red);
  readout_kernel<<<1, 128, 0, stream>>>(red, xw1, xb1, xw2, xb2,
                                        rw1, rb1, rw2, rb2, rw3, rb3, out);
}

// Round 5
// 1566.363 us; speedup vs baseline: 4.4038x; 1.3228x over previous
//
#include <hip/hip_runtime.h>
#include <hip/hip_fp16.h>
#include <math.h>

#define NN 50000
#define EE 800000

typedef _Float16 half8 __attribute__((ext_vector_type(8)));
typedef float floatx4 __attribute__((ext_vector_type(4)));

// ---------------------------------------------------------------------------
// Fold edge-encoder into msg_w1.
// ---------------------------------------------------------------------------
__global__ void fold_kernel(const float* __restrict__ ew, const float* __restrict__ eb,
                            const float* __restrict__ w1, const float* __restrict__ b1,
                            float* __restrict__ Wc, float* __restrict__ b1f) {
  int l = blockIdx.y, c = blockIdx.x, j = threadIdx.x;
  __shared__ float row[128];
  const float* w1l = w1 + (size_t)l * 385 * 128;
  if (c < 32) {
    row[j] = ew[c * 128 + j];
    __syncthreads();
    float acc = 0.f;
    for (int k = 0; k < 128; k++) acc += row[k] * w1l[(256 + k) * 128 + j];
    Wc[((size_t)l * 32 + c) * 128 + j] = acc;
  } else {
    row[j] = eb[j];
    __syncthreads();
    float acc = b1[l * 128 + j];
    for (int k = 0; k < 128; k++) acc += row[k] * w1l[(256 + k) * 128 + j];
    b1f[l * 128 + j] = acc;
  }
}

// ---------------------------------------------------------------------------
// Weight packing into fp16 MFMA B-fragment order (see round 2).
// ---------------------------------------------------------------------------
__global__ void prep_w(const float* __restrict__ src, _Float16* __restrict__ dst,
                       int K, int perm) {
  int l = blockIdx.y;
  int lane = threadIdx.x;
  int kc = blockIdx.x >> 3, nt = blockIdx.x & 7;
  int n = nt * 16 + (lane & 15);
  int k0 = kc * 32 + (lane >> 4) * 8;
  const float* s = src + (size_t)l * K * 128;
  _Float16 out[8];
  for (int j = 0; j < 8; j++) {
    int k = k0 + j;
    int ks = perm ? ((k & 7) * 16 + (k >> 3)) : k;
    out[j] = (_Float16)s[(size_t)ks * 128 + n];
  }
  _Float16* d = dst + (((size_t)l * gridDim.x + blockIdx.x) * 64 + lane) * 8;
  *(half8*)d = *(half8*)out;
}

__global__ void prep_msg1(const float* __restrict__ mw1, const float* __restrict__ Wc,
                          _Float16* __restrict__ dst) {
  int l = blockIdx.y;
  int lane = threadIdx.x;
  int kc = blockIdx.x >> 3, nt = blockIdx.x & 7;
  int n = nt * 16 + (lane & 15);
  int k0 = kc * 32 + (lane >> 4) * 8;
  _Float16 out[8];
  for (int j = 0; j < 8; j++) {
    int k = k0 + j;
    float v = (k < 256) ? mw1[((size_t)l * 385 + k) * 128 + n]
                        : Wc[((size_t)l * 32 + (k - 256)) * 128 + n];
    out[j] = (_Float16)v;
  }
  _Float16* d = dst + (((size_t)l * 72 + blockIdx.x) * 64 + lane) * 8;
  *(half8*)d = *(half8*)out;
}

// ---------------------------------------------------------------------------
// CSR build: histogram of dst, exclusive scan, slot-scatter + edge pre-permute.
// ---------------------------------------------------------------------------
__global__ void hist_kernel(const int* __restrict__ dstv, int* __restrict__ counts) {
  int e = blockIdx.x * 256 + threadIdx.x;
  if (e < EE) atomicAdd(&counts[dstv[e]], 1);
}

// single block, 256 threads; serial-carry chunked Hillis-Steele scan.
__global__ void scan_kernel(const int* __restrict__ counts, int* __restrict__ offs) {
  __shared__ int s[256];
  int t = threadIdx.x;
  int carry = 0;
  for (int chunk = 0; chunk < 196; chunk++) {
    int i = chunk * 256 + t;
    int v = (i < NN) ? counts[i] : 0;
    s[t] = v;
    __syncthreads();
    for (int off = 1; off < 256; off <<= 1) {
      int add = (t >= off) ? s[t - off] : 0;
      __syncthreads();
      s[t] += add;
      __syncthreads();
    }
    if (i < NN) offs[i] = carry + s[t] - v;
    carry += s[255];
    __syncthreads();
  }
}

// For each edge: p = offs[dst] + cursor[dst]++ ; write permuted src/dst/cong
// and fp16 edge features at position p.
__global__ void slot_kernel(const int* __restrict__ srcv, const int* __restrict__ dstv,
                            const float* __restrict__ cong, const float* __restrict__ ef,
                            const int* __restrict__ offs, int* __restrict__ cursor,
                            int* __restrict__ srcp, int* __restrict__ dstp,
                            float* __restrict__ cgp, _Float16* __restrict__ efh) {
  int e = blockIdx.x * 256 + threadIdx.x;
  if (e >= EE) return;
  int d = dstv[e], s = srcv[e];
  int p = offs[d] + atomicAdd(&cursor[d], 1);
  srcp[p] = s;
  dstp[p] = d;
  cgp[p] = cong[s];
  const float* sp = ef + (size_t)e * 32;
  _Float16* dp = efh + (size_t)p * 32;
  for (int i = 0; i < 4; i++) {
    float4 f = *(const float4*)(sp + i * 8);
    float4 g = *(const float4*)(sp + i * 8 + 4);
    half8 v;
    v[0] = (_Float16)f.x; v[1] = (_Float16)f.y; v[2] = (_Float16)f.z; v[3] = (_Float16)f.w;
    v[4] = (_Float16)g.x; v[5] = (_Float16)g.y; v[6] = (_Float16)g.z; v[7] = (_Float16)g.w;
    *(half8*)(dp + i * 8) = v;
  }
}

// ---------------------------------------------------------------------------
// Node encoder via MFMA.
// ---------------------------------------------------------------------------
__global__ void enc_mfma(const float* __restrict__ nf, const _Float16* __restrict__ Wenc,
                         const float* __restrict__ bn, float* __restrict__ x,
                         _Float16* __restrict__ xh) {
  int t = threadIdx.x, wave = t >> 6, lane = t & 63;
  int quad = lane >> 4, l15 = lane & 15;
  long nb0 = (long)blockIdx.x * 64 + wave * 16;
  long rn = nb0 + l15;
  if (rn >= NN) rn = NN - 1;

  floatx4 acc[8] = {};
  for (int kc = 0; kc < 2; kc++) {
    const float* p = nf + rn * 64 + kc * 32 + quad * 8;
    float4 f0 = *(const float4*)p;
    float4 f1 = *(const float4*)(p + 4);
    half8 a;
    a[0] = (_Float16)f0.x; a[1] = (_Float16)f0.y;
    a[2] = (_Float16)f0.z; a[3] = (_Float16)f0.w;
    a[4] = (_Float16)f1.x; a[5] = (_Float16)f1.y;
    a[6] = (_Float16)f1.z; a[7] = (_Float16)f1.w;
    const _Float16* bp = Wenc + (size_t)(kc * 8) * 512 + lane * 8;
    for (int nt = 0; nt < 8; nt++) {
      half8 b = *(const half8*)(bp + nt * 512);
      acc[nt] = __builtin_amdgcn_mfma_f32_16x16x32_f16(a, b, acc[nt], 0, 0, 0);
    }
  }
  float bv[8];
  for (int nt = 0; nt < 8; nt++) bv[nt] = bn[nt * 16 + l15];
  for (int reg = 0; reg < 4; reg++) {
    long n = nb0 + quad * 4 + reg;
    if (n < NN) {
      for (int nt = 0; nt < 8; nt++) {
        int col = nt * 16 + l15;
        float v = acc[nt][reg] + bv[nt];
        x[n * 128 + col] = v;
        xh[n * 128 + col] = (_Float16)v;
      }
    }
  }
}

// ---------------------------------------------------------------------------
// Message + segmented-reduce scatter. Edges pre-sorted by dst.
// block 256 = 4 waves; 32 edges/wave, 128/block.
// GEMM1 (K=288) -> relu -> LDS h-tile -> GEMM2 -> m-tile in same LDS ->
// per-column segmented reduction over sorted dst runs -> few pk-fp16 atomics.
// ---------------------------------------------------------------------------
__global__ __launch_bounds__(256, 4) void msg_kernel(
    const _Float16* __restrict__ xh, const _Float16* __restrict__ efh,
    const float* __restrict__ cgp,
    const int* __restrict__ srcp, const int* __restrict__ dstp,
    const _Float16* __restrict__ Wp1, const _Float16* __restrict__ Wp2,
    const float* __restrict__ wcong, const float* __restrict__ b1f,
    const float* __restrict__ b2, __half* __restrict__ agg) {
  __shared__ __align__(16) _Float16 buf[128][136];  // h-tile, then m-tile
  __shared__ int s_src[128], s_dst[128];
  __shared__ float s_cg[128];
  int t = threadIdx.x, wave = t >> 6, lane = t & 63;
  int quad = lane >> 4, l15 = lane & 15;
  long eb0 = (long)blockIdx.x * 128;
  if (t < 128) {
    s_src[t] = srcp[eb0 + t];
    s_dst[t] = dstp[eb0 + t];
    s_cg[t] = cgp[eb0 + t];
  }
  __syncthreads();
  int web = wave * 32;

  floatx4 acc[2][8] = {};
#pragma unroll
  for (int kc = 0; kc < 8; kc++) {
    const int* rows = (kc < 4) ? s_src : s_dst;
    int ko = (kc & 3) * 32 + quad * 8;
    half8 a0 = *(const half8*)(xh + (size_t)rows[web + l15] * 128 + ko);
    half8 a1 = *(const half8*)(xh + (size_t)rows[web + 16 + l15] * 128 + ko);
    const _Float16* bp = Wp1 + (size_t)(kc * 8) * 512 + lane * 8;
#pragma unroll
    for (int nt = 0; nt < 8; nt++) {
      half8 b = *(const half8*)(bp + nt * 512);
      acc[0][nt] = __builtin_amdgcn_mfma_f32_16x16x32_f16(a0, b, acc[0][nt], 0, 0, 0);
      acc[1][nt] = __builtin_amdgcn_mfma_f32_16x16x32_f16(a1, b, acc[1][nt], 0, 0, 0);
    }
  }
  {  // edge-feature phase (kc = 8), contiguous fp16
    half8 a0 = *(const half8*)(efh + (eb0 + web + l15) * 32 + quad * 8);
    half8 a1 = *(const half8*)(efh + (eb0 + web + 16 + l15) * 32 + quad * 8);
    const _Float16* bp = Wp1 + (size_t)64 * 512 + lane * 8;
#pragma unroll
    for (int nt = 0; nt < 8; nt++) {
      half8 b = *(const half8*)(bp + nt * 512);
      acc[0][nt] = __builtin_amdgcn_mfma_f32_16x16x32_f16(a0, b, acc[0][nt], 0, 0, 0);
      acc[1][nt] = __builtin_amdgcn_mfma_f32_16x16x32_f16(a1, b, acc[1][nt], 0, 0, 0);
    }
  }

  // epilogue 1: congestion + bias, relu, write h-tile (k' = l15*8+nt layout)
  float wcv[8], bbv[8];
  for (int nt = 0; nt < 8; nt++) {
    int col = nt * 16 + l15;
    wcv[nt] = wcong[col];
    bbv[nt] = b1f[col];
  }
  for (int mt = 0; mt < 2; mt++)
    for (int reg = 0; reg < 4; reg++) {
      int rl = mt * 16 + quad * 4 + reg;
      float cg = s_cg[web + rl];
      half8 hv;
      for (int nt = 0; nt < 8; nt++)
        hv[nt] = (_Float16)fmaxf(acc[mt][nt][reg] + cg * wcv[nt] + bbv[nt], 0.f);
      *(half8*)&buf[web + rl][l15 * 8] = hv;
    }
  // per-wave slab: this wave only reads its own rows below; no block sync needed

  floatx4 acc2[2][8] = {};
#pragma unroll
  for (int kc = 0; kc < 4; kc++) {
    half8 a0 = *(const half8*)&buf[web + l15][kc * 32 + quad * 8];
    half8 a1 = *(const half8*)&buf[web + 16 + l15][kc * 32 + quad * 8];
    const _Float16* bp = Wp2 + (size_t)(kc * 8) * 512 + lane * 8;
#pragma unroll
    for (int nt = 0; nt < 8; nt++) {
      half8 b = *(const half8*)(bp + nt * 512);
      acc2[0][nt] = __builtin_amdgcn_mfma_f32_16x16x32_f16(a0, b, acc2[0][nt], 0, 0, 0);
      acc2[1][nt] = __builtin_amdgcn_mfma_f32_16x16x32_f16(a1, b, acc2[1][nt], 0, 0, 0);
    }
  }

  // epilogue 2: bias, pack column pairs via lane^1 shuffle, write m-tile
  // (reuses the same LDS slab this wave just finished reading).
  float b2v[8];
  for (int nt = 0; nt < 8; nt++) b2v[nt] = b2[nt * 16 + l15];
  for (int mt = 0; mt < 2; mt++)
    for (int reg = 0; reg < 4; reg++) {
      int row = web + mt * 16 + quad * 4 + reg;
      for (int nt = 0; nt < 8; nt++) {
        float v = acc2[mt][nt][reg] + b2v[nt];
        float p = __shfl_xor(v, 1);
        if ((l15 & 1) == 0) {
          __half2 h = __halves2half2(__float2half(v), __float2half(p));
          *(__half2*)&buf[row][nt * 16 + l15] = h;
        }
      }
    }
  __syncthreads();

  // segmented reduction: thread = (row-quarter q, col-pair cp); dst sorted so
  // the run-boundary branch is wave-uniform. Partial runs flush pk-fp16 atomics.
  {
    int cp = t & 63;
    int q = t >> 6;
    int r0 = q * 32;
    int cur = s_dst[r0];
    float a0 = 0.f, a1 = 0.f;
    for (int i = r0; i < r0 + 32; i++) {
      int d = s_dst[i];
      if (d != cur) {
        unsafeAtomicAdd((__half2*)(agg + (long)cur * 128 + cp * 2),
                        __halves2half2(__float2half(a0), __float2half(a1)));
        a0 = a1 = 0.f;
        cur = d;
      }
      __half2 v = *(__half2*)&buf[i][cp * 2];
      float2 f = __half22float2(v);
      a0 += f.x;
      a1 += f.y;
    }
    unsafeAtomicAdd((__half2*)(agg + (long)cur * 128 + cp * 2),
                    __halves2half2(__float2half(a0), __float2half(a1)));
  }
}

// ---------------------------------------------------------------------------
// Update + residual + layernorm (MFMA). agg fp16 -> direct A-fragment loads.
// ---------------------------------------------------------------------------
__global__ __launch_bounds__(256, 2) void upd_kernel(
    float* __restrict__ x, _Float16* __restrict__ xh, const _Float16* __restrict__ agg,
    const _Float16* __restrict__ Wp1, const _Float16* __restrict__ Wp2,
    const float* __restrict__ b1, const float* __restrict__ b2,
    const float* __restrict__ g, const float* __restrict__ bb) {
  __shared__ __align__(16) _Float16 hs[4][16][136];
  int t = threadIdx.x, wave = t >> 6, lane = t & 63;
  int quad = lane >> 4, l15 = lane & 15;
  long nb0 = (long)blockIdx.x * 64 + wave * 16;

  floatx4 acc[8] = {};
  {
    long n = nb0 + l15;
    long rn = n < NN ? n : NN - 1;
    for (int kc = 0; kc < 8; kc++) {
      half8 a;
      if (kc < 4) {
        a = *(const half8*)(xh + rn * 128 + kc * 32 + quad * 8);
      } else {
        a = *(const half8*)(agg + rn * 128 + (kc - 4) * 32 + quad * 8);
      }
      const _Float16* bp = Wp1 + (size_t)(kc * 8) * 512 + lane * 8;
      for (int nt = 0; nt < 8; nt++) {
        half8 b = *(const half8*)(bp + nt * 512);
        acc[nt] = __builtin_amdgcn_mfma_f32_16x16x32_f16(a, b, acc[nt], 0, 0, 0);
      }
    }
  }

  float bbv[8];
  for (int nt = 0; nt < 8; nt++) bbv[nt] = b1[nt * 16 + l15];
  for (int reg = 0; reg < 4; reg++) {
    half8 hv;
    for (int nt = 0; nt < 8; nt++)
      hv[nt] = (_Float16)fmaxf(acc[nt][reg] + bbv[nt], 0.f);
    *(half8*)&hs[wave][quad * 4 + reg][l15 * 8] = hv;
  }
  __syncthreads();

  floatx4 acc2[8] = {};
  for (int kc = 0; kc < 4; kc++) {
    half8 a = *(const half8*)&hs[wave][l15][kc * 32 + quad * 8];
    const _Float16* bp = Wp2 + (size_t)(kc * 8) * 512 + lane * 8;
    for (int nt = 0; nt < 8; nt++) {
      half8 b = *(const half8*)(bp + nt * 512);
      acc2[nt] = __builtin_amdgcn_mfma_f32_16x16x32_f16(a, b, acc2[nt], 0, 0, 0);
    }
  }

  float b2v[8], gv[8], bv[8];
  for (int nt = 0; nt < 8; nt++) {
    int col = nt * 16 + l15;
    b2v[nt] = b2[col]; gv[nt] = g[col]; bv[nt] = bb[col];
  }
  for (int reg = 0; reg < 4; reg++) {
    long n = nb0 + quad * 4 + reg;
    bool ok = n < NN;
    long rn = ok ? n : NN - 1;
    float y[8];
    float s = 0.f;
    for (int nt = 0; nt < 8; nt++) {
      y[nt] = x[rn * 128 + nt * 16 + l15] + acc2[nt][reg] + b2v[nt];
      s += y[nt];
    }
    s += __shfl_xor(s, 1); s += __shfl_xor(s, 2);
    s += __shfl_xor(s, 4); s += __shfl_xor(s, 8);
    float mu = s * (1.f / 128.f);
    float q = 0.f;
    for (int nt = 0; nt < 8; nt++) {
      y[nt] -= mu;
      q += y[nt] * y[nt];
    }
    q += __shfl_xor(q, 1); q += __shfl_xor(q, 2);
    q += __shfl_xor(q, 4); q += __shfl_xor(q, 8);
    float rstd = rsqrtf(q * (1.f / 128.f) + 1e-5f);
    if (ok) {
      for (int nt = 0; nt < 8; nt++) {
        float o = y[nt] * rstd * gv[nt] + bv[nt];
        x[n * 128 + nt * 16 + l15] = o;
        xh[n * 128 + nt * 16 + l15] = (_Float16)o;
      }
    }
  }
}

// ---------------------------------------------------------------------------
// Global reductions: per-channel sum of x + unrouted count.
// ---------------------------------------------------------------------------
__global__ void reduce_kernel(const float* __restrict__ x, const int* __restrict__ umask,
                              float* __restrict__ red) {
  int t = threadIdx.x;
  long base = (long)blockIdx.x * 196;
  int j = t & 127, half = t >> 7;
  float acc = 0.f;
  for (int i = 0; i < 98; i++) {
    long n = base + half + 2L * i;
    if (n < NN) acc += x[n * 128 + j];
  }
  __shared__ float sr[2][128];
  __shared__ float sm[4];
  sr[half][j] = acc;
  float mv = 0.f;
  {
    long n = base + t;
    if (t < 196 && n < NN) mv = (float)umask[n];
  }
  for (int off = 32; off; off >>= 1) mv += __shfl_xor(mv, off);
  if ((t & 63) == 0) sm[t >> 6] = mv;
  __syncthreads();
  if (t < 128) atomicAdd(&red[t], sr[0][t] + sr[1][t]);
  if (t == 0) atomicAdd(&red[128], sm[0] + sm[1] + sm[2] + sm[3]);
}

// ---------------------------------------------------------------------------
// Readout head.
// ---------------------------------------------------------------------------
__global__ void readout_kernel(const float* __restrict__ red,
                               const float* __restrict__ xw1, const float* __restrict__ xb1,
                               const float* __restrict__ xw2, const float* __restrict__ xb2,
                               const float* __restrict__ rw1, const float* __restrict__ rb1,
                               const float* __restrict__ rw2, const float* __restrict__ rb2,
                               const float* __restrict__ rw3, const float* __restrict__ rb3,
                               float* __restrict__ out) {
  __shared__ float sa[128], sb[128], sc[128];
  int j = threadIdx.x;
  const float inv = 1.f / (float)NN;
  float ge = red[j] * inv;
  float uf = red[128] * inv;
  float u1 = fmaxf(uf * xw1[j] + xb1[j], 0.f);
  sa[j] = u1;
  sb[j] = ge;
  __syncthreads();
  float u2 = xb2[j];
  for (int k = 0; k < 128; k++) u2 += sa[k] * xw2[k * 128 + j];
  sc[j] = u2;
  __syncthreads();
  float h1 = rb1[j];
  for (int k = 0; k < 128; k++) h1 += sb[k] * rw1[k * 128 + j];
  for (int k = 0; k < 128; k++) h1 += sc[k] * rw1[(128 + k) * 128 + j];
  h1 = fmaxf(h1, 0.f);
  __syncthreads();
  sa[j] = h1;
  __syncthreads();
  float h2 = 0.f;
  if (j < 64) {
    h2 = rb2[j];
    for (int k = 0; k < 128; k++) h2 += sa[k] * rw2[k * 64 + j];
    h2 = fmaxf(h2, 0.f);
  }
  __syncthreads();
  if (j < 64) sb[j] = h2;
  __syncthreads();
  if (j == 0) {
    float a = rb3[0];
    for (int k = 0; k < 64; k++) a += sb[k] * rw3[k];
    out[0] = 1.f / (1.f + expf(-a));
  }
}

// ---------------------------------------------------------------------------
extern "C" void kernel_launch(void* const* d_in, const int* in_sizes, int n_in,
                              void* d_out, int out_size, void* d_ws, size_t ws_size,
                              hipStream_t stream) {
  const float* nf   = (const float*)d_in[0];
  const float* ef   = (const float*)d_in[1];
  const float* cong = (const float*)d_in[2];
  const int*   eidx = (const int*)d_in[3];
  const int*   um   = (const int*)d_in[4];
  const float* enw  = (const float*)d_in[5];
  const float* enb  = (const float*)d_in[6];
  const float* eew  = (const float*)d_in[7];
  const float* eeb  = (const float*)d_in[8];
  const float* mw1  = (const float*)d_in[9];
  const float* mb1  = (const float*)d_in[10];
  const float* mw2  = (const float*)d_in[11];
  const float* mb2  = (const float*)d_in[12];
  const float* uw1  = (const float*)d_in[13];
  const float* ub1  = (const float*)d_in[14];
  const float* uw2  = (const float*)d_in[15];
  const float* ub2  = (const float*)d_in[16];
  const float* lnw  = (const float*)d_in[17];
  const float* lnb  = (const float*)d_in[18];
  const float* xw1  = (const float*)d_in[19];
  const float* xb1  = (const float*)d_in[20];
  const float* xw2  = (const float*)d_in[21];
  const float* xb2  = (const float*)d_in[22];
  const float* rw1  = (const float*)d_in[23];
  const float* rb1  = (const float*)d_in[24];
  const float* rw2  = (const float*)d_in[25];
  const float* rb2  = (const float*)d_in[26];
  const float* rw3  = (const float*)d_in[27];
  const float* rb3  = (const float*)d_in[28];
  float* out = (float*)d_out;

  char* W = (char*)d_ws;
  float*    x     = (float*)(W + 0);             // 25,600,000
  _Float16* xh    = (_Float16*)(W + 25600000);   // 12,800,000
  __half*   agg   = (__half*)(W + 38400000);     // 12,800,000
  _Float16* efh   = (_Float16*)(W + 51200000);   // 51,200,000
  int*      srcp  = (int*)(W + 102400000);       // 3,200,000
  int*      dstp  = (int*)(W + 105600000);       // 3,200,000
  float*    cgp   = (float*)(W + 108800000);     // 3,200,000
  int*      counts= (int*)(W + 112000000);       // 200,000
  int*      cursor= (int*)(W + 112200000);       // 200,000
  int*      offs  = (int*)(W + 112400000);       // 200,000
  _Float16* Wm1   = (_Float16*)(W + 112600000);  // 294,912
  _Float16* Wm2   = (_Float16*)(W + 112894912);  // 131,072
  _Float16* Wu1   = (_Float16*)(W + 113025984);  // 262,144
  _Float16* Wu2   = (_Float16*)(W + 113288128);  // 131,072
  _Float16* Wen   = (_Float16*)(W + 113419200);  // 16,384
  float*    Wc    = (float*)(W + 113435584);     // 65,536
  float*    b1f   = (float*)(W + 113501120);     // 2,048
  float*    red   = (float*)(W + 113503168);     // 516

  const int* srcv = eidx;
  const int* dstv = eidx + EE;

  // CSR build + edge permute
  (void)hipMemsetAsync(counts, 0, 400000, stream);  // counts + cursor
  hist_kernel<<<3125, 256, 0, stream>>>(dstv, counts);
  scan_kernel<<<1, 256, 0, stream>>>(counts, offs);
  slot_kernel<<<3125, 256, 0, stream>>>(srcv, dstv, cong, ef, offs, cursor,
                                        srcp, dstp, cgp, efh);

  // weight prep + encoder
  fold_kernel<<<dim3(33, 4), 128, 0, stream>>>(eew, eeb, mw1, mb1, Wc, b1f);
  prep_msg1<<<dim3(72, 4), 64, 0, stream>>>(mw1, Wc, Wm1);
  prep_w<<<dim3(32, 4), 64, 0, stream>>>(mw2, Wm2, 128, 1);
  prep_w<<<dim3(64, 4), 64, 0, stream>>>(uw1, Wu1, 256, 0);
  prep_w<<<dim3(32, 4), 64, 0, stream>>>(uw2, Wu2, 128, 1);
  prep_w<<<dim3(16, 1), 64, 0, stream>>>(enw, Wen, 64, 0);
  enc_mfma<<<782, 256, 0, stream>>>(nf, Wen, enb, x, xh);

  for (int l = 0; l < 4; l++) {
    (void)hipMemsetAsync(agg, 0, (size_t)NN * 128 * sizeof(__half), stream);
    msg_kernel<<<6250, 256, 0, stream>>>(
        xh, efh, cgp, srcp, dstp,
        Wm1 + (size_t)l * 72 * 512, Wm2 + (size_t)l * 32 * 512,
        mw1 + (size_t)l * 385 * 128 + (size_t)384 * 128,
        b1f + l * 128, mb2 + l * 128, agg);
    upd_kernel<<<782, 256, 0, stream>>>(
        x, xh, (const _Float16*)agg,
        Wu1 + (size_t)l * 64 * 512, Wu2 + (size_t)l * 32 * 512,
        ub1 + l * 128, ub2 + l * 128, lnw + l * 128, lnb + l * 128);
  }

  (void)hipMemsetAsync(red, 0, 129 * sizeof(float), stream);
  reduce_kernel<<<256, 256, 0, stream>>>(x, um, red);
  readout_kernel<<<1, 128, 0, stream>>>(red, xw1, xb1, xw2, xb2,
                                        rw1, rb1, rw2, rb2, rw3, rb3, out);
}

// Round 6
// 1310.706 us; speedup vs baseline: 5.2628x; 1.1951x over previous
//
#include <hip/hip_runtime.h>
#include <hip/hip_fp16.h>
#include <math.h>

#define NN 50000
#define EE 800000

typedef _Float16 half8 __attribute__((ext_vector_type(8)));
typedef float floatx4 __attribute__((ext_vector_type(4)));

// ---------------------------------------------------------------------------
// Fold edge-encoder into msg_w1.
// ---------------------------------------------------------------------------
__global__ void fold_kernel(const float* __restrict__ ew, const float* __restrict__ eb,
                            const float* __restrict__ w1, const float* __restrict__ b1,
                            float* __restrict__ Wc, float* __restrict__ b1f) {
  int l = blockIdx.y, c = blockIdx.x, j = threadIdx.x;
  __shared__ float row[128];
  const float* w1l = w1 + (size_t)l * 385 * 128;
  if (c < 32) {
    row[j] = ew[c * 128 + j];
    __syncthreads();
    float acc = 0.f;
    for (int k = 0; k < 128; k++) acc += row[k] * w1l[(256 + k) * 128 + j];
    Wc[((size_t)l * 32 + c) * 128 + j] = acc;
  } else {
    row[j] = eb[j];
    __syncthreads();
    float acc = b1[l * 128 + j];
    for (int k = 0; k < 128; k++) acc += row[k] * w1l[(256 + k) * 128 + j];
    b1f[l * 128 + j] = acc;
  }
}

// ---------------------------------------------------------------------------
// Weight packing into fp16 MFMA B-fragment order.
// ---------------------------------------------------------------------------
__global__ void prep_w(const float* __restrict__ src, _Float16* __restrict__ dst,
                       int K, int perm) {
  int l = blockIdx.y;
  int lane = threadIdx.x;
  int kc = blockIdx.x >> 3, nt = blockIdx.x & 7;
  int n = nt * 16 + (lane & 15);
  int k0 = kc * 32 + (lane >> 4) * 8;
  const float* s = src + (size_t)l * K * 128;
  _Float16 out[8];
  for (int j = 0; j < 8; j++) {
    int k = k0 + j;
    int ks = perm ? ((k & 7) * 16 + (k >> 3)) : k;
    out[j] = (_Float16)s[(size_t)ks * 128 + n];
  }
  _Float16* d = dst + (((size_t)l * gridDim.x + blockIdx.x) * 64 + lane) * 8;
  *(half8*)d = *(half8*)out;
}

__global__ void prep_msg1(const float* __restrict__ mw1, const float* __restrict__ Wc,
                          _Float16* __restrict__ dst) {
  int l = blockIdx.y;
  int lane = threadIdx.x;
  int kc = blockIdx.x >> 3, nt = blockIdx.x & 7;
  int n = nt * 16 + (lane & 15);
  int k0 = kc * 32 + (lane >> 4) * 8;
  _Float16 out[8];
  for (int j = 0; j < 8; j++) {
    int k = k0 + j;
    float v = (k < 256) ? mw1[((size_t)l * 385 + k) * 128 + n]
                        : Wc[((size_t)l * 32 + (k - 256)) * 128 + n];
    out[j] = (_Float16)v;
  }
  _Float16* d = dst + (((size_t)l * 72 + blockIdx.x) * 64 + lane) * 8;
  *(half8*)d = *(half8*)out;
}

// ---------------------------------------------------------------------------
// CSR build: histogram, scan, slot-scatter + edge pre-permute.
// ---------------------------------------------------------------------------
__global__ void hist_kernel(const int* __restrict__ dstv, int* __restrict__ counts) {
  int e = blockIdx.x * 256 + threadIdx.x;
  if (e < EE) atomicAdd(&counts[dstv[e]], 1);
}

// single block, 1024 threads; wave-shuffle scan, 49 chunks.
__global__ void scan_kernel(const int* __restrict__ counts, int* __restrict__ offs) {
  __shared__ int ws[16];
  int t = threadIdx.x, lane = t & 63, w = t >> 6;
  int carry = 0;
  for (int chunk = 0; chunk < 49; chunk++) {
    int i = chunk * 1024 + t;
    int v = (i < NN) ? counts[i] : 0;
    int s = v;
    for (int off = 1; off < 64; off <<= 1) {
      int u = __shfl_up(s, off);
      if (lane >= off) s += u;
    }
    if (lane == 63) ws[w] = s;
    __syncthreads();
    if (w == 0) {
      int u = (lane < 16) ? ws[lane] : 0;
      for (int off = 1; off < 16; off <<= 1) {
        int x = __shfl_up(u, off);
        if (lane >= off && lane < 16) u += x;
      }
      if (lane < 16) ws[lane] = u;
    }
    __syncthreads();
    int wbase = (w > 0) ? ws[w - 1] : 0;
    int total = ws[15];
    if (i < NN) offs[i] = carry + wbase + s - v;  // exclusive
    carry += total;
    __syncthreads();
  }
}

__global__ void slot_kernel(const int* __restrict__ srcv, const int* __restrict__ dstv,
                            const float* __restrict__ cong, const float* __restrict__ ef,
                            const int* __restrict__ offs, int* __restrict__ cursor,
                            int* __restrict__ srcp, int* __restrict__ dstp,
                            float* __restrict__ cgp, _Float16* __restrict__ efh) {
  int e = blockIdx.x * 256 + threadIdx.x;
  if (e >= EE) return;
  int d = dstv[e], s = srcv[e];
  int p = offs[d] + atomicAdd(&cursor[d], 1);
  srcp[p] = s;
  dstp[p] = d;
  cgp[p] = cong[s];
  const float* sp = ef + (size_t)e * 32;
  _Float16* dp = efh + (size_t)p * 32;
  for (int i = 0; i < 4; i++) {
    float4 f = *(const float4*)(sp + i * 8);
    float4 g = *(const float4*)(sp + i * 8 + 4);
    half8 v;
    v[0] = (_Float16)f.x; v[1] = (_Float16)f.y; v[2] = (_Float16)f.z; v[3] = (_Float16)f.w;
    v[4] = (_Float16)g.x; v[5] = (_Float16)g.y; v[6] = (_Float16)g.z; v[7] = (_Float16)g.w;
    *(half8*)(dp + i * 8) = v;
  }
}

// ---------------------------------------------------------------------------
// Node encoder via MFMA.
// ---------------------------------------------------------------------------
__global__ void enc_mfma(const float* __restrict__ nf, const _Float16* __restrict__ Wenc,
                         const float* __restrict__ bn, float* __restrict__ x,
                         _Float16* __restrict__ xh) {
  int t = threadIdx.x, wave = t >> 6, lane = t & 63;
  int quad = lane >> 4, l15 = lane & 15;
  long nb0 = (long)blockIdx.x * 64 + wave * 16;
  long rn = nb0 + l15;
  if (rn >= NN) rn = NN - 1;

  floatx4 acc[8] = {};
  for (int kc = 0; kc < 2; kc++) {
    const float* p = nf + rn * 64 + kc * 32 + quad * 8;
    float4 f0 = *(const float4*)p;
    float4 f1 = *(const float4*)(p + 4);
    half8 a;
    a[0] = (_Float16)f0.x; a[1] = (_Float16)f0.y;
    a[2] = (_Float16)f0.z; a[3] = (_Float16)f0.w;
    a[4] = (_Float16)f1.x; a[5] = (_Float16)f1.y;
    a[6] = (_Float16)f1.z; a[7] = (_Float16)f1.w;
    const _Float16* bp = Wenc + (size_t)(kc * 8) * 512 + lane * 8;
    for (int nt = 0; nt < 8; nt++) {
      half8 b = *(const half8*)(bp + nt * 512);
      acc[nt] = __builtin_amdgcn_mfma_f32_16x16x32_f16(a, b, acc[nt], 0, 0, 0);
    }
  }
  float bv[8];
  for (int nt = 0; nt < 8; nt++) bv[nt] = bn[nt * 16 + l15];
  for (int reg = 0; reg < 4; reg++) {
    long n = nb0 + quad * 4 + reg;
    if (n < NN) {
      for (int nt = 0; nt < 8; nt++) {
        int col = nt * 16 + l15;
        float v = acc[nt][reg] + bv[nt];
        x[n * 128 + col] = v;
        xh[n * 128 + col] = (_Float16)v;
      }
    }
  }
}

// ---------------------------------------------------------------------------
// Message + segmented-reduce scatter, barrier-free decoupled pipeline.
// block 256 = 4 waves; 32 edges/wave, fully wave-local:
//  1. wave loads its src/dst/cong indices
//  2. stages its 32 src rows into its LDS slab (8 independent 16B loads)
//  3. preloads dst + ef A-frags into regs (dst sorted -> L1 hits)
//  4. GEMM1 kc0-3 from LDS (hides in-flight dst loads), kc4-8 from regs
//  5. relu -> slab, GEMM2, m-tile -> slab, seg-reduce -> few pk-fp16 atomics
// ---------------------------------------------------------------------------
__global__ __launch_bounds__(256, 4) void msg_kernel(
    const _Float16* __restrict__ xh, const _Float16* __restrict__ efh,
    const float* __restrict__ cgp,
    const int* __restrict__ srcp, const int* __restrict__ dstp,
    const _Float16* __restrict__ Wp1, const _Float16* __restrict__ Wp2,
    const float* __restrict__ wcong, const float* __restrict__ b1f,
    const float* __restrict__ b2, __half* __restrict__ agg) {
  __shared__ __align__(16) _Float16 buf[128][136];  // src-tile, h-tile, m-tile
  __shared__ int s_src[128], s_dst[128];
  __shared__ float s_cg[128];
  int t = threadIdx.x, wave = t >> 6, lane = t & 63;
  int quad = lane >> 4, l15 = lane & 15;
  long eb0 = (long)blockIdx.x * 128;
  int web = wave * 32;

  // 1. wave-local index load (no block barrier anywhere in this kernel)
  if (lane < 32) {
    int e = web + lane;
    s_src[e] = srcp[eb0 + e];
    s_dst[e] = dstp[eb0 + e];
    s_cg[e] = cgp[eb0 + e];
  }

  // 2. stage this wave's 32 src rows into buf[web..web+31]
  {
    half8 stg[8];
#pragma unroll
    for (int it = 0; it < 8; it++) {
      int row = it * 4 + quad;
      stg[it] = *(const half8*)(xh + (size_t)s_src[web + row] * 128 + l15 * 8);
    }
#pragma unroll
    for (int it = 0; it < 8; it++) {
      int row = it * 4 + quad;
      *(half8*)&buf[web + row][l15 * 8] = stg[it];
    }
  }

  // 3. preload dst A-frags (kc 4..7) and ef frags (kc 8) into registers
  half8 ad0[5], ad1[5];
#pragma unroll
  for (int kc = 0; kc < 4; kc++) {
    int ko = kc * 32 + quad * 8;
    ad0[kc] = *(const half8*)(xh + (size_t)s_dst[web + l15] * 128 + ko);
    ad1[kc] = *(const half8*)(xh + (size_t)s_dst[web + 16 + l15] * 128 + ko);
  }
  ad0[4] = *(const half8*)(efh + (eb0 + web + l15) * 32 + quad * 8);
  ad1[4] = *(const half8*)(efh + (eb0 + web + 16 + l15) * 32 + quad * 8);

  floatx4 acc[2][8] = {};
  // 4a. src half from LDS
#pragma unroll
  for (int kc = 0; kc < 4; kc++) {
    int ko = kc * 32 + quad * 8;
    half8 a0 = *(const half8*)&buf[web + l15][ko];
    half8 a1 = *(const half8*)&buf[web + 16 + l15][ko];
    const _Float16* bp = Wp1 + (size_t)(kc * 8) * 512 + lane * 8;
#pragma unroll
    for (int nt = 0; nt < 8; nt++) {
      half8 b = *(const half8*)(bp + nt * 512);
      acc[0][nt] = __builtin_amdgcn_mfma_f32_16x16x32_f16(a0, b, acc[0][nt], 0, 0, 0);
      acc[1][nt] = __builtin_amdgcn_mfma_f32_16x16x32_f16(a1, b, acc[1][nt], 0, 0, 0);
    }
  }
  // 4b. dst half + ef from registers
#pragma unroll
  for (int kc = 0; kc < 5; kc++) {
    const _Float16* bp = Wp1 + (size_t)((kc + 4) * 8) * 512 + lane * 8;
#pragma unroll
    for (int nt = 0; nt < 8; nt++) {
      half8 b = *(const half8*)(bp + nt * 512);
      acc[0][nt] = __builtin_amdgcn_mfma_f32_16x16x32_f16(ad0[kc], b, acc[0][nt], 0, 0, 0);
      acc[1][nt] = __builtin_amdgcn_mfma_f32_16x16x32_f16(ad1[kc], b, acc[1][nt], 0, 0, 0);
    }
  }

  // 5. epilogue 1: congestion + bias, relu, write h-tile (k' = l15*8+nt layout)
  float wcv[8], bbv[8];
  for (int nt = 0; nt < 8; nt++) {
    int col = nt * 16 + l15;
    wcv[nt] = wcong[col];
    bbv[nt] = b1f[col];
  }
  for (int mt = 0; mt < 2; mt++)
    for (int reg = 0; reg < 4; reg++) {
      int rl = mt * 16 + quad * 4 + reg;
      float cg = s_cg[web + rl];
      half8 hv;
      for (int nt = 0; nt < 8; nt++)
        hv[nt] = (_Float16)fmaxf(acc[mt][nt][reg] + cg * wcv[nt] + bbv[nt], 0.f);
      *(half8*)&buf[web + rl][l15 * 8] = hv;
    }

  floatx4 acc2[2][8] = {};
#pragma unroll
  for (int kc = 0; kc < 4; kc++) {
    half8 a0 = *(const half8*)&buf[web + l15][kc * 32 + quad * 8];
    half8 a1 = *(const half8*)&buf[web + 16 + l15][kc * 32 + quad * 8];
    const _Float16* bp = Wp2 + (size_t)(kc * 8) * 512 + lane * 8;
#pragma unroll
    for (int nt = 0; nt < 8; nt++) {
      half8 b = *(const half8*)(bp + nt * 512);
      acc2[0][nt] = __builtin_amdgcn_mfma_f32_16x16x32_f16(a0, b, acc2[0][nt], 0, 0, 0);
      acc2[1][nt] = __builtin_amdgcn_mfma_f32_16x16x32_f16(a1, b, acc2[1][nt], 0, 0, 0);
    }
  }

  // epilogue 2: bias, pack column pairs via lane^1 shuffle, write m-tile
  float b2v[8];
  for (int nt = 0; nt < 8; nt++) b2v[nt] = b2[nt * 16 + l15];
  for (int mt = 0; mt < 2; mt++)
    for (int reg = 0; reg < 4; reg++) {
      int row = web + mt * 16 + quad * 4 + reg;
      for (int nt = 0; nt < 8; nt++) {
        float v = acc2[mt][nt][reg] + b2v[nt];
        float p = __shfl_xor(v, 1);
        if ((l15 & 1) == 0) {
          __half2 h = __halves2half2(__float2half(v), __float2half(p));
          *(__half2*)&buf[row][nt * 16 + l15] = h;
        }
      }
    }

  // seg-reduce over this wave's own 32 sorted rows (wave-local, no barrier)
  {
    int cp = lane;  // column pair 0..63
    int r0 = web;
    int cur = s_dst[r0];
    float a0 = 0.f, a1 = 0.f;
    for (int i = r0; i < r0 + 32; i++) {
      int d = s_dst[i];
      if (d != cur) {
        unsafeAtomicAdd((__half2*)(agg + (long)cur * 128 + cp * 2),
                        __halves2half2(__float2half(a0), __float2half(a1)));
        a0 = a1 = 0.f;
        cur = d;
      }
      __half2 v = *(__half2*)&buf[i][cp * 2];
      float2 f = __half22float2(v);
      a0 += f.x;
      a1 += f.y;
    }
    unsafeAtomicAdd((__half2*)(agg + (long)cur * 128 + cp * 2),
                    __halves2half2(__float2half(a0), __float2half(a1)));
  }
}

// ---------------------------------------------------------------------------
// Update + residual + layernorm (MFMA). agg fp16 -> direct A-fragment loads.
// ---------------------------------------------------------------------------
__global__ __launch_bounds__(256, 3) void upd_kernel(
    float* __restrict__ x, _Float16* __restrict__ xh, const _Float16* __restrict__ agg,
    const _Float16* __restrict__ Wp1, const _Float16* __restrict__ Wp2,
    const float* __restrict__ b1, const float* __restrict__ b2,
    const float* __restrict__ g, const float* __restrict__ bb) {
  __shared__ __align__(16) _Float16 hs[4][16][136];
  int t = threadIdx.x, wave = t >> 6, lane = t & 63;
  int quad = lane >> 4, l15 = lane & 15;
  long nb0 = (long)blockIdx.x * 64 + wave * 16;

  floatx4 acc[8] = {};
  {
    long n = nb0 + l15;
    long rn = n < NN ? n : NN - 1;
    for (int kc = 0; kc < 8; kc++) {
      half8 a;
      if (kc < 4) {
        a = *(const half8*)(xh + rn * 128 + kc * 32 + quad * 8);
      } else {
        a = *(const half8*)(agg + rn * 128 + (kc - 4) * 32 + quad * 8);
      }
      const _Float16* bp = Wp1 + (size_t)(kc * 8) * 512 + lane * 8;
      for (int nt = 0; nt < 8; nt++) {
        half8 b = *(const half8*)(bp + nt * 512);
        acc[nt] = __builtin_amdgcn_mfma_f32_16x16x32_f16(a, b, acc[nt], 0, 0, 0);
      }
    }
  }

  float bbv[8];
  for (int nt = 0; nt < 8; nt++) bbv[nt] = b1[nt * 16 + l15];
  for (int reg = 0; reg < 4; reg++) {
    half8 hv;
    for (int nt = 0; nt < 8; nt++)
      hv[nt] = (_Float16)fmaxf(acc[nt][reg] + bbv[nt], 0.f);
    *(half8*)&hs[wave][quad * 4 + reg][l15 * 8] = hv;
  }
  __syncthreads();

  floatx4 acc2[8] = {};
  for (int kc = 0; kc < 4; kc++) {
    half8 a = *(const half8*)&hs[wave][l15][kc * 32 + quad * 8];
    const _Float16* bp = Wp2 + (size_t)(kc * 8) * 512 + lane * 8;
    for (int nt = 0; nt < 8; nt++) {
      half8 b = *(const half8*)(bp + nt * 512);
      acc2[nt] = __builtin_amdgcn_mfma_f32_16x16x32_f16(a, b, acc2[nt], 0, 0, 0);
    }
  }

  float b2v[8], gv[8], bv[8];
  for (int nt = 0; nt < 8; nt++) {
    int col = nt * 16 + l15;
    b2v[nt] = b2[col]; gv[nt] = g[col]; bv[nt] = bb[col];
  }
  for (int reg = 0; reg < 4; reg++) {
    long n = nb0 + quad * 4 + reg;
    bool ok = n < NN;
    long rn = ok ? n : NN - 1;
    float y[8];
    float s = 0.f;
    for (int nt = 0; nt < 8; nt++) {
      y[nt] = x[rn * 128 + nt * 16 + l15] + acc2[nt][reg] + b2v[nt];
      s += y[nt];
    }
    s += __shfl_xor(s, 1); s += __shfl_xor(s, 2);
    s += __shfl_xor(s, 4); s += __shfl_xor(s, 8);
    float mu = s * (1.f / 128.f);
    float q = 0.f;
    for (int nt = 0; nt < 8; nt++) {
      y[nt] -= mu;
      q += y[nt] * y[nt];
    }
    q += __shfl_xor(q, 1); q += __shfl_xor(q, 2);
    q += __shfl_xor(q, 4); q += __shfl_xor(q, 8);
    float rstd = rsqrtf(q * (1.f / 128.f) + 1e-5f);
    if (ok) {
      for (int nt = 0; nt < 8; nt++) {
        float o = y[nt] * rstd * gv[nt] + bv[nt];
        x[n * 128 + nt * 16 + l15] = o;
        xh[n * 128 + nt * 16 + l15] = (_Float16)o;
      }
    }
  }
}

// ---------------------------------------------------------------------------
// Global reductions: per-channel sum of x + unrouted count.
// ---------------------------------------------------------------------------
__global__ void reduce_kernel(const float* __restrict__ x, const int* __restrict__ umask,
                              float* __restrict__ red) {
  int t = threadIdx.x;
  long base = (long)blockIdx.x * 196;
  int j = t & 127, half = t >> 7;
  float acc = 0.f;
  for (int i = 0; i < 98; i++) {
    long n = base + half + 2L * i;
    if (n < NN) acc += x[n * 128 + j];
  }
  __shared__ float sr[2][128];
  __shared__ float sm[4];
  sr[half][j] = acc;
  float mv = 0.f;
  {
    long n = base + t;
    if (t < 196 && n < NN) mv = (float)umask[n];
  }
  for (int off = 32; off; off >>= 1) mv += __shfl_xor(mv, off);
  if ((t & 63) == 0) sm[t >> 6] = mv;
  __syncthreads();
  if (t < 128) atomicAdd(&red[t], sr[0][t] + sr[1][t]);
  if (t == 0) atomicAdd(&red[128], sm[0] + sm[1] + sm[2] + sm[3]);
}

// ---------------------------------------------------------------------------
// Readout head.
// ---------------------------------------------------------------------------
__global__ void readout_kernel(const float* __restrict__ red,
                               const float* __restrict__ xw1, const float* __restrict__ xb1,
                               const float* __restrict__ xw2, const float* __restrict__ xb2,
                               const float* __restrict__ rw1, const float* __restrict__ rb1,
                               const float* __restrict__ rw2, const float* __restrict__ rb2,
                               const float* __restrict__ rw3, const float* __restrict__ rb3,
                               float* __restrict__ out) {
  __shared__ float sa[128], sb[128], sc[128];
  int j = threadIdx.x;
  const float inv = 1.f / (float)NN;
  float ge = red[j] * inv;
  float uf = red[128] * inv;
  float u1 = fmaxf(uf * xw1[j] + xb1[j], 0.f);
  sa[j] = u1;
  sb[j] = ge;
  __syncthreads();
  float u2 = xb2[j];
  for (int k = 0; k < 128; k++) u2 += sa[k] * xw2[k * 128 + j];
  sc[j] = u2;
  __syncthreads();
  float h1 = rb1[j];
  for (int k = 0; k < 128; k++) h1 += sb[k] * rw1[k * 128 + j];
  for (int k = 0; k < 128; k++) h1 += sc[k] * rw1[(128 + k) * 128 + j];
  h1 = fmaxf(h1, 0.f);
  __syncthreads();
  sa[j] = h1;
  __syncthreads();
  float h2 = 0.f;
  if (j < 64) {
    h2 = rb2[j];
    for (int k = 0; k < 128; k++) h2 += sa[k] * rw2[k * 64 + j];
    h2 = fmaxf(h2, 0.f);
  }
  __syncthreads();
  if (j < 64) sb[j] = h2;
  __syncthreads();
  if (j == 0) {
    float a = rb3[0];
    for (int k = 0; k < 64; k++) a += sb[k] * rw3[k];
    out[0] = 1.f / (1.f + expf(-a));
  }
}

// ---------------------------------------------------------------------------
extern "C" void kernel_launch(void* const* d_in, const int* in_sizes, int n_in,
                              void* d_out, int out_size, void* d_ws, size_t ws_size,
                              hipStream_t stream) {
  const float* nf   = (const float*)d_in[0];
  const float* ef   = (const float*)d_in[1];
  const float* cong = (const float*)d_in[2];
  const int*   eidx = (const int*)d_in[3];
  const int*   um   = (const int*)d_in[4];
  const float* enw  = (const float*)d_in[5];
  const float* enb  = (const float*)d_in[6];
  const float* eew  = (const float*)d_in[7];
  const float* eeb  = (const float*)d_in[8];
  const float* mw1  = (const float*)d_in[9];
  const float* mb1  = (const float*)d_in[10];
  const float* mw2  = (const float*)d_in[11];
  const float* mb2  = (const float*)d_in[12];
  const float* uw1  = (const float*)d_in[13];
  const float* ub1  = (const float*)d_in[14];
  const float* uw2  = (const float*)d_in[15];
  const float* ub2  = (const float*)d_in[16];
  const float* lnw  = (const float*)d_in[17];
  const float* lnb  = (const float*)d_in[18];
  const float* xw1  = (const float*)d_in[19];
  const float* xb1  = (const float*)d_in[20];
  const float* xw2  = (const float*)d_in[21];
  const float* xb2  = (const float*)d_in[22];
  const float* rw1  = (const float*)d_in[23];
  const float* rb1  = (const float*)d_in[24];
  const float* rw2  = (const float*)d_in[25];
  const float* rb2  = (const float*)d_in[26];
  const float* rw3  = (const float*)d_in[27];
  const float* rb3  = (const float*)d_in[28];
  float* out = (float*)d_out;

  char* W = (char*)d_ws;
  float*    x     = (float*)(W + 0);             // 25,600,000
  _Float16* xh    = (_Float16*)(W + 25600000);   // 12,800,000
  __half*   agg   = (__half*)(W + 38400000);     // 12,800,000
  _Float16* efh   = (_Float16*)(W + 51200000);   // 51,200,000
  int*      srcp  = (int*)(W + 102400000);       // 3,200,000
  int*      dstp  = (int*)(W + 105600000);       // 3,200,000
  float*    cgp   = (float*)(W + 108800000);     // 3,200,000
  int*      counts= (int*)(W + 112000000);       // 200,000
  int*      cursor= (int*)(W + 112200000);       // 200,000
  int*      offs  = (int*)(W + 112400000);       // 200,000
  _Float16* Wm1   = (_Float16*)(W + 112600000);  // 294,912
  _Float16* Wm2   = (_Float16*)(W + 112894912);  // 131,072
  _Float16* Wu1   = (_Float16*)(W + 113025984);  // 262,144
  _Float16* Wu2   = (_Float16*)(W + 113288128);  // 131,072
  _Float16* Wen   = (_Float16*)(W + 113419200);  // 16,384
  float*    Wc    = (float*)(W + 113435584);     // 65,536
  float*    b1f   = (float*)(W + 113501120);     // 2,048
  float*    red   = (float*)(W + 113503168);     // 516

  const int* srcv = eidx;
  const int* dstv = eidx + EE;

  // CSR build + edge permute
  (void)hipMemsetAsync(counts, 0, 400000, stream);  // counts + cursor
  hist_kernel<<<3125, 256, 0, stream>>>(dstv, counts);
  scan_kernel<<<1, 1024, 0, stream>>>(counts, offs);
  slot_kernel<<<3125, 256, 0, stream>>>(srcv, dstv, cong, ef, offs, cursor,
                                        srcp, dstp, cgp, efh);

  // weight prep + encoder
  fold_kernel<<<dim3(33, 4), 128, 0, stream>>>(eew, eeb, mw1, mb1, Wc, b1f);
  prep_msg1<<<dim3(72, 4), 64, 0, stream>>>(mw1, Wc, Wm1);
  prep_w<<<dim3(32, 4), 64, 0, stream>>>(mw2, Wm2, 128, 1);
  prep_w<<<dim3(64, 4), 64, 0, stream>>>(uw1, Wu1, 256, 0);
  prep_w<<<dim3(32, 4), 64, 0, stream>>>(uw2, Wu2, 128, 1);
  prep_w<<<dim3(16, 1), 64, 0, stream>>>(enw, Wen, 64, 0);
  enc_mfma<<<782, 256, 0, stream>>>(nf, Wen, enb, x, xh);

  for (int l = 0; l < 4; l++) {
    (void)hipMemsetAsync(agg, 0, (size_t)NN * 128 * sizeof(__half), stream);
    msg_kernel<<<6250, 256, 0, stream>>>(
        xh, efh, cgp, srcp, dstp,
        Wm1 + (size_t)l * 72 * 512, Wm2 + (size_t)l * 32 * 512,
        mw1 + (size_t)l * 385 * 128 + (size_t)384 * 128,
        b1f + l * 128, mb2 + l * 128, agg);
    upd_kernel<<<782, 256, 0, stream>>>(
        x, xh, (const _Float16*)agg,
        Wu1 + (size_t)l * 64 * 512, Wu2 + (size_t)l * 32 * 512,
        ub1 + l * 128, ub2 + l * 128, lnw + l * 128, lnb + l * 128);
  }

  (void)hipMemsetAsync(red, 0, 129 * sizeof(float), stream);
  reduce_kernel<<<256, 256, 0, stream>>>(x, um, red);
  readout_kernel<<<1, 128, 0, stream>>>(red, xw1, xb1, xw2, xb2,
                                        rw1, rb1, rw2, rb2, rw3, rb3, out);
}

// Round 7
// 1246.986 us; speedup vs baseline: 5.5317x; 1.0511x over previous
//
#include <hip/hip_runtime.h>
#include <hip/hip_fp16.h>
#include <math.h>

#define NN 50000
#define EE 800000

typedef _Float16 half8 __attribute__((ext_vector_type(8)));
typedef float floatx4 __attribute__((ext_vector_type(4)));

// ---------------------------------------------------------------------------
// Fold edge-encoder into msg_w1.
// ---------------------------------------------------------------------------
__global__ void fold_kernel(const float* __restrict__ ew, const float* __restrict__ eb,
                            const float* __restrict__ w1, const float* __restrict__ b1,
                            float* __restrict__ Wc, float* __restrict__ b1f) {
  int l = blockIdx.y, c = blockIdx.x, j = threadIdx.x;
  __shared__ float row[128];
  const float* w1l = w1 + (size_t)l * 385 * 128;
  if (c < 32) {
    row[j] = ew[c * 128 + j];
    __syncthreads();
    float acc = 0.f;
    for (int k = 0; k < 128; k++) acc += row[k] * w1l[(256 + k) * 128 + j];
    Wc[((size_t)l * 32 + c) * 128 + j] = acc;
  } else {
    row[j] = eb[j];
    __syncthreads();
    float acc = b1[l * 128 + j];
    for (int k = 0; k < 128; k++) acc += row[k] * w1l[(256 + k) * 128 + j];
    b1f[l * 128 + j] = acc;
  }
}

// ---------------------------------------------------------------------------
// Weight packing into fp16 MFMA B-fragment order.
// ---------------------------------------------------------------------------
__global__ void prep_w(const float* __restrict__ src, _Float16* __restrict__ dst,
                       int K, int perm) {
  int l = blockIdx.y;
  int lane = threadIdx.x;
  int kc = blockIdx.x >> 3, nt = blockIdx.x & 7;
  int n = nt * 16 + (lane & 15);
  int k0 = kc * 32 + (lane >> 4) * 8;
  const float* s = src + (size_t)l * K * 128;
  _Float16 out[8];
  for (int j = 0; j < 8; j++) {
    int k = k0 + j;
    int ks = perm ? ((k & 7) * 16 + (k >> 3)) : k;
    out[j] = (_Float16)s[(size_t)ks * 128 + n];
  }
  _Float16* d = dst + (((size_t)l * gridDim.x + blockIdx.x) * 64 + lane) * 8;
  *(half8*)d = *(half8*)out;
}

__global__ void prep_msg1(const float* __restrict__ mw1, const float* __restrict__ Wc,
                          _Float16* __restrict__ dst) {
  int l = blockIdx.y;
  int lane = threadIdx.x;
  int kc = blockIdx.x >> 3, nt = blockIdx.x & 7;
  int n = nt * 16 + (lane & 15);
  int k0 = kc * 32 + (lane >> 4) * 8;
  _Float16 out[8];
  for (int j = 0; j < 8; j++) {
    int k = k0 + j;
    float v = (k < 256) ? mw1[((size_t)l * 385 + k) * 128 + n]
                        : Wc[((size_t)l * 32 + (k - 256)) * 128 + n];
    out[j] = (_Float16)v;
  }
  _Float16* d = dst + (((size_t)l * 72 + blockIdx.x) * 64 + lane) * 8;
  *(half8*)d = *(half8*)out;
}

// ---------------------------------------------------------------------------
// CSR build: histogram, scan, slot-scatter + edge pre-permute.
// ---------------------------------------------------------------------------
__global__ void hist_kernel(const int* __restrict__ dstv, int* __restrict__ counts) {
  int e = blockIdx.x * 256 + threadIdx.x;
  if (e < EE) atomicAdd(&counts[dstv[e]], 1);
}

// single block, 1024 threads; wave-shuffle scan, 49 chunks.
__global__ void scan_kernel(const int* __restrict__ counts, int* __restrict__ offs) {
  __shared__ int ws[16];
  int t = threadIdx.x, lane = t & 63, w = t >> 6;
  int carry = 0;
  for (int chunk = 0; chunk < 49; chunk++) {
    int i = chunk * 1024 + t;
    int v = (i < NN) ? counts[i] : 0;
    int s = v;
    for (int off = 1; off < 64; off <<= 1) {
      int u = __shfl_up(s, off);
      if (lane >= off) s += u;
    }
    if (lane == 63) ws[w] = s;
    __syncthreads();
    if (w == 0) {
      int u = (lane < 16) ? ws[lane] : 0;
      for (int off = 1; off < 16; off <<= 1) {
        int x = __shfl_up(u, off);
        if (lane >= off && lane < 16) u += x;
      }
      if (lane < 16) ws[lane] = u;
    }
    __syncthreads();
    int wbase = (w > 0) ? ws[w - 1] : 0;
    int total = ws[15];
    if (i < NN) offs[i] = carry + wbase + s - v;  // exclusive
    carry += total;
    __syncthreads();
  }
}

__global__ void slot_kernel(const int* __restrict__ srcv, const int* __restrict__ dstv,
                            const float* __restrict__ cong, const float* __restrict__ ef,
                            const int* __restrict__ offs, int* __restrict__ cursor,
                            int* __restrict__ srcp, int* __restrict__ dstp,
                            float* __restrict__ cgp, _Float16* __restrict__ efh) {
  int e = blockIdx.x * 256 + threadIdx.x;
  if (e >= EE) return;
  int d = dstv[e], s = srcv[e];
  int p = offs[d] + atomicAdd(&cursor[d], 1);
  srcp[p] = s;
  dstp[p] = d;
  cgp[p] = cong[s];
  const float* sp = ef + (size_t)e * 32;
  _Float16* dp = efh + (size_t)p * 32;
  for (int i = 0; i < 4; i++) {
    float4 f = *(const float4*)(sp + i * 8);
    float4 g = *(const float4*)(sp + i * 8 + 4);
    half8 v;
    v[0] = (_Float16)f.x; v[1] = (_Float16)f.y; v[2] = (_Float16)f.z; v[3] = (_Float16)f.w;
    v[4] = (_Float16)g.x; v[5] = (_Float16)g.y; v[6] = (_Float16)g.z; v[7] = (_Float16)g.w;
    *(half8*)(dp + i * 8) = v;
  }
}

// ---------------------------------------------------------------------------
// Node encoder via MFMA.
// ---------------------------------------------------------------------------
__global__ void enc_mfma(const float* __restrict__ nf, const _Float16* __restrict__ Wenc,
                         const float* __restrict__ bn, float* __restrict__ x,
                         _Float16* __restrict__ xh) {
  int t = threadIdx.x, wave = t >> 6, lane = t & 63;
  int quad = lane >> 4, l15 = lane & 15;
  long nb0 = (long)blockIdx.x * 64 + wave * 16;
  long rn = nb0 + l15;
  if (rn >= NN) rn = NN - 1;

  floatx4 acc[8] = {};
  for (int kc = 0; kc < 2; kc++) {
    const float* p = nf + rn * 64 + kc * 32 + quad * 8;
    float4 f0 = *(const float4*)p;
    float4 f1 = *(const float4*)(p + 4);
    half8 a;
    a[0] = (_Float16)f0.x; a[1] = (_Float16)f0.y;
    a[2] = (_Float16)f0.z; a[3] = (_Float16)f0.w;
    a[4] = (_Float16)f1.x; a[5] = (_Float16)f1.y;
    a[6] = (_Float16)f1.z; a[7] = (_Float16)f1.w;
    const _Float16* bp = Wenc + (size_t)(kc * 8) * 512 + lane * 8;
    for (int nt = 0; nt < 8; nt++) {
      half8 b = *(const half8*)(bp + nt * 512);
      acc[nt] = __builtin_amdgcn_mfma_f32_16x16x32_f16(a, b, acc[nt], 0, 0, 0);
    }
  }
  float bv[8];
  for (int nt = 0; nt < 8; nt++) bv[nt] = bn[nt * 16 + l15];
  for (int reg = 0; reg < 4; reg++) {
    long n = nb0 + quad * 4 + reg;
    if (n < NN) {
      for (int nt = 0; nt < 8; nt++) {
        int col = nt * 16 + l15;
        float v = acc[nt][reg] + bv[nt];
        x[n * 128 + col] = v;
        xh[n * 128 + col] = (_Float16)v;
      }
    }
  }
}

// ---------------------------------------------------------------------------
// Message kernel v7: N-split tiled GEMM. Block = 4 waves, 128 edges.
// Wave w computes N-tiles {2w, 2w+1} (32 cols) for ALL 128 edges:
//   - weights per wave = 26 KB (4x less than v6) and L1-shared across waves
//   - src rows staged in LDS once, read by all waves
//   - dst A-frags from global (a sorted 128-edge tile has ~8 unique dsts -> L1)
//   - h k-perm round-trip through the same LDS slab; m-tile ditto
//   - seg-reduce batch-loads 32 values to regs (pipelined) before the scan
// ---------------------------------------------------------------------------
__global__ __launch_bounds__(256, 4) void msg_kernel(
    const _Float16* __restrict__ xh, const _Float16* __restrict__ efh,
    const float* __restrict__ cgp,
    const int* __restrict__ srcp, const int* __restrict__ dstp,
    const _Float16* __restrict__ Wp1, const _Float16* __restrict__ Wp2,
    const float* __restrict__ wcong, const float* __restrict__ b1f,
    const float* __restrict__ b2, __half* __restrict__ agg) {
  __shared__ __align__(16) _Float16 As[128][136];  // src-tile -> h-tile -> m-tile
  __shared__ int s_src[128], s_dst[128];
  __shared__ float s_cg[128];
  int t = threadIdx.x, wave = t >> 6, lane = t & 63;
  int quad = lane >> 4, l15 = lane & 15;
  long eb0 = (long)blockIdx.x * 128;
  if (t < 128) {
    s_src[t] = srcp[eb0 + t];
    s_dst[t] = dstp[eb0 + t];
    s_cg[t] = cgp[eb0 + t];
  }
  __syncthreads();

  // stage src rows (wave stages its quarter)
  {
    int web = wave * 32;
    half8 stg[8];
#pragma unroll
    for (int it = 0; it < 8; it++)
      stg[it] = *(const half8*)(xh + (size_t)s_src[web + it * 4 + quad] * 128 + l15 * 8);
#pragma unroll
    for (int it = 0; it < 8; it++)
      *(half8*)&As[web + it * 4 + quad][l15 * 8] = stg[it];
  }
  // hoist this lane's dst row ids (used for all 4 dst kc phases)
  int drow[8];
#pragma unroll
  for (int mt = 0; mt < 8; mt++) drow[mt] = s_dst[mt * 16 + l15];
  __syncthreads();

  int nb = wave * 2;  // N-tile pair {nb, nb+1}
  floatx4 acc[8][2] = {};

  // GEMM1 kc 0..3: src operand from LDS
#pragma unroll
  for (int kc = 0; kc < 4; kc++) {
    int ko = kc * 32 + quad * 8;
    const _Float16* bp = Wp1 + ((size_t)(kc * 8 + nb)) * 512 + lane * 8;
    half8 b0 = *(const half8*)bp;
    half8 b1v = *(const half8*)(bp + 512);
#pragma unroll
    for (int mt = 0; mt < 8; mt++) {
      half8 a = *(const half8*)&As[mt * 16 + l15][ko];
      acc[mt][0] = __builtin_amdgcn_mfma_f32_16x16x32_f16(a, b0, acc[mt][0], 0, 0, 0);
      acc[mt][1] = __builtin_amdgcn_mfma_f32_16x16x32_f16(a, b1v, acc[mt][1], 0, 0, 0);
    }
  }
  // GEMM1 kc 4..7: dst operand from global (L1-resident: ~8 unique rows/block)
#pragma unroll
  for (int kc = 0; kc < 4; kc++) {
    int ko = kc * 32 + quad * 8;
    const _Float16* bp = Wp1 + ((size_t)((kc + 4) * 8 + nb)) * 512 + lane * 8;
    half8 b0 = *(const half8*)bp;
    half8 b1v = *(const half8*)(bp + 512);
#pragma unroll
    for (int mt = 0; mt < 8; mt++) {
      half8 a = *(const half8*)(xh + (size_t)drow[mt] * 128 + ko);
      acc[mt][0] = __builtin_amdgcn_mfma_f32_16x16x32_f16(a, b0, acc[mt][0], 0, 0, 0);
      acc[mt][1] = __builtin_amdgcn_mfma_f32_16x16x32_f16(a, b1v, acc[mt][1], 0, 0, 0);
    }
  }
  // GEMM1 kc 8: edge features (contiguous fp16)
  {
    const _Float16* bp = Wp1 + ((size_t)(64 + nb)) * 512 + lane * 8;
    half8 b0 = *(const half8*)bp;
    half8 b1v = *(const half8*)(bp + 512);
#pragma unroll
    for (int mt = 0; mt < 8; mt++) {
      half8 a = *(const half8*)(efh + (eb0 + mt * 16 + l15) * 32 + quad * 8);
      acc[mt][0] = __builtin_amdgcn_mfma_f32_16x16x32_f16(a, b0, acc[mt][0], 0, 0, 0);
      acc[mt][1] = __builtin_amdgcn_mfma_f32_16x16x32_f16(a, b1v, acc[mt][1], 0, 0, 0);
    }
  }
  __syncthreads();  // all waves done reading src tile from As

  // epilogue 1: congestion + bias, relu; write h into As with k-perm layout
  // (value of column c = nt*16+l15 stored at offset l15*8+nt; our two nt are
  //  adjacent -> single 4B write per (mt,reg))
  {
    float wc0 = wcong[nb * 16 + l15], wc1 = wcong[(nb + 1) * 16 + l15];
    float bb0 = b1f[nb * 16 + l15], bb1 = b1f[(nb + 1) * 16 + l15];
#pragma unroll
    for (int mt = 0; mt < 8; mt++)
#pragma unroll
      for (int reg = 0; reg < 4; reg++) {
        int row = mt * 16 + quad * 4 + reg;
        float cg = s_cg[row];
        __half2 hv = __halves2half2(
            __float2half(fmaxf(acc[mt][0][reg] + cg * wc0 + bb0, 0.f)),
            __float2half(fmaxf(acc[mt][1][reg] + cg * wc1 + bb1, 0.f)));
        *(__half2*)&As[row][l15 * 8 + nb] = hv;
      }
  }
  __syncthreads();

  // GEMM2: h (perm layout) x Wp2 (rows pre-permuted to match)
  floatx4 acc2[8][2] = {};
#pragma unroll
  for (int kc = 0; kc < 4; kc++) {
    const _Float16* bp = Wp2 + ((size_t)(kc * 8 + nb)) * 512 + lane * 8;
    half8 b0 = *(const half8*)bp;
    half8 b1v = *(const half8*)(bp + 512);
#pragma unroll
    for (int mt = 0; mt < 8; mt++) {
      half8 a = *(const half8*)&As[mt * 16 + l15][kc * 32 + quad * 8];
      acc2[mt][0] = __builtin_amdgcn_mfma_f32_16x16x32_f16(a, b0, acc2[mt][0], 0, 0, 0);
      acc2[mt][1] = __builtin_amdgcn_mfma_f32_16x16x32_f16(a, b1v, acc2[mt][1], 0, 0, 0);
    }
  }
  __syncthreads();  // all waves done reading h from As

  // epilogue 2: bias; pack adjacent columns via lane^1 shuffle; m -> As
  {
    float c0 = b2[nb * 16 + l15], c1 = b2[(nb + 1) * 16 + l15];
#pragma unroll
    for (int mt = 0; mt < 8; mt++)
#pragma unroll
      for (int reg = 0; reg < 4; reg++) {
        int row = mt * 16 + quad * 4 + reg;
#pragma unroll
        for (int ntp = 0; ntp < 2; ntp++) {
          float v = acc2[mt][ntp][reg] + (ntp ? c1 : c0);
          float p = __shfl_xor(v, 1);
          if ((l15 & 1) == 0) {
            __half2 h = __halves2half2(__float2half(v), __float2half(p));
            *(__half2*)&As[row][(nb + ntp) * 16 + l15] = h;
          }
        }
      }
  }
  __syncthreads();

  // segmented reduction over sorted dst runs; batch-load 32 values to regs
  {
    int cp = t & 63;   // column pair (2cp, 2cp+1)
    int q = t >> 6;    // row quarter
    int r0 = q * 32;
    __half2 vals[32];
#pragma unroll
    for (int i = 0; i < 32; i++) vals[i] = *(__half2*)&As[r0 + i][cp * 2];
    int cur = s_dst[r0];
    float a0 = 0.f, a1 = 0.f;
    for (int i = 0; i < 32; i++) {
      int d = s_dst[r0 + i];
      if (d != cur) {
        unsafeAtomicAdd((__half2*)(agg + (long)cur * 128 + cp * 2),
                        __halves2half2(__float2half(a0), __float2half(a1)));
        a0 = a1 = 0.f;
        cur = d;
      }
      float2 f = __half22float2(vals[i]);
      a0 += f.x;
      a1 += f.y;
    }
    unsafeAtomicAdd((__half2*)(agg + (long)cur * 128 + cp * 2),
                    __halves2half2(__float2half(a0), __float2half(a1)));
  }
}

// ---------------------------------------------------------------------------
// Update + residual + layernorm (MFMA). agg fp16 -> direct A-fragment loads.
// ---------------------------------------------------------------------------
__global__ __launch_bounds__(256, 3) void upd_kernel(
    float* __restrict__ x, _Float16* __restrict__ xh, const _Float16* __restrict__ agg,
    const _Float16* __restrict__ Wp1, const _Float16* __restrict__ Wp2,
    const float* __restrict__ b1, const float* __restrict__ b2,
    const float* __restrict__ g, const float* __restrict__ bb) {
  __shared__ __align__(16) _Float16 hs[4][16][136];
  int t = threadIdx.x, wave = t >> 6, lane = t & 63;
  int quad = lane >> 4, l15 = lane & 15;
  long nb0 = (long)blockIdx.x * 64 + wave * 16;

  floatx4 acc[8] = {};
  {
    long n = nb0 + l15;
    long rn = n < NN ? n : NN - 1;
    for (int kc = 0; kc < 8; kc++) {
      half8 a;
      if (kc < 4) {
        a = *(const half8*)(xh + rn * 128 + kc * 32 + quad * 8);
      } else {
        a = *(const half8*)(agg + rn * 128 + (kc - 4) * 32 + quad * 8);
      }
      const _Float16* bp = Wp1 + (size_t)(kc * 8) * 512 + lane * 8;
      for (int nt = 0; nt < 8; nt++) {
        half8 b = *(const half8*)(bp + nt * 512);
        acc[nt] = __builtin_amdgcn_mfma_f32_16x16x32_f16(a, b, acc[nt], 0, 0, 0);
      }
    }
  }

  float bbv[8];
  for (int nt = 0; nt < 8; nt++) bbv[nt] = b1[nt * 16 + l15];
  for (int reg = 0; reg < 4; reg++) {
    half8 hv;
    for (int nt = 0; nt < 8; nt++)
      hv[nt] = (_Float16)fmaxf(acc[nt][reg] + bbv[nt], 0.f);
    *(half8*)&hs[wave][quad * 4 + reg][l15 * 8] = hv;
  }
  __syncthreads();

  floatx4 acc2[8] = {};
  for (int kc = 0; kc < 4; kc++) {
    half8 a = *(const half8*)&hs[wave][l15][kc * 32 + quad * 8];
    const _Float16* bp = Wp2 + (size_t)(kc * 8) * 512 + lane * 8;
    for (int nt = 0; nt < 8; nt++) {
      half8 b = *(const half8*)(bp + nt * 512);
      acc2[nt] = __builtin_amdgcn_mfma_f32_16x16x32_f16(a, b, acc2[nt], 0, 0, 0);
    }
  }

  float b2v[8], gv[8], bv[8];
  for (int nt = 0; nt < 8; nt++) {
    int col = nt * 16 + l15;
    b2v[nt] = b2[col]; gv[nt] = g[col]; bv[nt] = bb[col];
  }
  for (int reg = 0; reg < 4; reg++) {
    long n = nb0 + quad * 4 + reg;
    bool ok = n < NN;
    long rn = ok ? n : NN - 1;
    float y[8];
    float s = 0.f;
    for (int nt = 0; nt < 8; nt++) {
      y[nt] = x[rn * 128 + nt * 16 + l15] + acc2[nt][reg] + b2v[nt];
      s += y[nt];
    }
    s += __shfl_xor(s, 1); s += __shfl_xor(s, 2);
    s += __shfl_xor(s, 4); s += __shfl_xor(s, 8);
    float mu = s * (1.f / 128.f);
    float q = 0.f;
    for (int nt = 0; nt < 8; nt++) {
      y[nt] -= mu;
      q += y[nt] * y[nt];
    }
    q += __shfl_xor(q, 1); q += __shfl_xor(q, 2);
    q += __shfl_xor(q, 4); q += __shfl_xor(q, 8);
    float rstd = rsqrtf(q * (1.f / 128.f) + 1e-5f);
    if (ok) {
      for (int nt = 0; nt < 8; nt++) {
        float o = y[nt] * rstd * gv[nt] + bv[nt];
        x[n * 128 + nt * 16 + l15] = o;
        xh[n * 128 + nt * 16 + l15] = (_Float16)o;
      }
    }
  }
}

// ---------------------------------------------------------------------------
// Global reductions: per-channel sum of x + unrouted count.
// ---------------------------------------------------------------------------
__global__ void reduce_kernel(const float* __restrict__ x, const int* __restrict__ umask,
                              float* __restrict__ red) {
  int t = threadIdx.x;
  long base = (long)blockIdx.x * 196;
  int j = t & 127, half = t >> 7;
  float acc = 0.f;
  for (int i = 0; i < 98; i++) {
    long n = base + half + 2L * i;
    if (n < NN) acc += x[n * 128 + j];
  }
  __shared__ float sr[2][128];
  __shared__ float sm[4];
  sr[half][j] = acc;
  float mv = 0.f;
  {
    long n = base + t;
    if (t < 196 && n < NN) mv = (float)umask[n];
  }
  for (int off = 32; off; off >>= 1) mv += __shfl_xor(mv, off);
  if ((t & 63) == 0) sm[t >> 6] = mv;
  __syncthreads();
  if (t < 128) atomicAdd(&red[t], sr[0][t] + sr[1][t]);
  if (t == 0) atomicAdd(&red[128], sm[0] + sm[1] + sm[2] + sm[3]);
}

// ---------------------------------------------------------------------------
// Readout head.
// ---------------------------------------------------------------------------
__global__ void readout_kernel(const float* __restrict__ red,
                               const float* __restrict__ xw1, const float* __restrict__ xb1,
                               const float* __restrict__ xw2, const float* __restrict__ xb2,
                               const float* __restrict__ rw1, const float* __restrict__ rb1,
                               const float* __restrict__ rw2, const float* __restrict__ rb2,
                               const float* __restrict__ rw3, const float* __restrict__ rb3,
                               float* __restrict__ out) {
  __shared__ float sa[128], sb[128], sc[128];
  int j = threadIdx.x;
  const float inv = 1.f / (float)NN;
  float ge = red[j] * inv;
  float uf = red[128] * inv;
  float u1 = fmaxf(uf * xw1[j] + xb1[j], 0.f);
  sa[j] = u1;
  sb[j] = ge;
  __syncthreads();
  float u2 = xb2[j];
  for (int k = 0; k < 128; k++) u2 += sa[k] * xw2[k * 128 + j];
  sc[j] = u2;
  __syncthreads();
  float h1 = rb1[j];
  for (int k = 0; k < 128; k++) h1 += sb[k] * rw1[k * 128 + j];
  for (int k = 0; k < 128; k++) h1 += sc[k] * rw1[(128 + k) * 128 + j];
  h1 = fmaxf(h1, 0.f);
  __syncthreads();
  sa[j] = h1;
  __syncthreads();
  float h2 = 0.f;
  if (j < 64) {
    h2 = rb2[j];
    for (int k = 0; k < 128; k++) h2 += sa[k] * rw2[k * 64 + j];
    h2 = fmaxf(h2, 0.f);
  }
  __syncthreads();
  if (j < 64) sb[j] = h2;
  __syncthreads();
  if (j == 0) {
    float a = rb3[0];
    for (int k = 0; k < 64; k++) a += sb[k] * rw3[k];
    out[0] = 1.f / (1.f + expf(-a));
  }
}

// ---------------------------------------------------------------------------
extern "C" void kernel_launch(void* const* d_in, const int* in_sizes, int n_in,
                              void* d_out, int out_size, void* d_ws, size_t ws_size,
                              hipStream_t stream) {
  const float* nf   = (const float*)d_in[0];
  const float* ef   = (const float*)d_in[1];
  const float* cong = (const float*)d_in[2];
  const int*   eidx = (const int*)d_in[3];
  const int*   um   = (const int*)d_in[4];
  const float* enw  = (const float*)d_in[5];
  const float* enb  = (const float*)d_in[6];
  const float* eew  = (const float*)d_in[7];
  const float* eeb  = (const float*)d_in[8];
  const float* mw1  = (const float*)d_in[9];
  const float* mb1  = (const float*)d_in[10];
  const float* mw2  = (const float*)d_in[11];
  const float* mb2  = (const float*)d_in[12];
  const float* uw1  = (const float*)d_in[13];
  const float* ub1  = (const float*)d_in[14];
  const float* uw2  = (const float*)d_in[15];
  const float* ub2  = (const float*)d_in[16];
  const float* lnw  = (const float*)d_in[17];
  const float* lnb  = (const float*)d_in[18];
  const float* xw1  = (const float*)d_in[19];
  const float* xb1  = (const float*)d_in[20];
  const float* xw2  = (const float*)d_in[21];
  const float* xb2  = (const float*)d_in[22];
  const float* rw1  = (const float*)d_in[23];
  const float* rb1  = (const float*)d_in[24];
  const float* rw2  = (const float*)d_in[25];
  const float* rb2  = (const float*)d_in[26];
  const float* rw3  = (const float*)d_in[27];
  const float* rb3  = (const float*)d_in[28];
  float* out = (float*)d_out;

  char* W = (char*)d_ws;
  float*    x     = (float*)(W + 0);             // 25,600,000
  _Float16* xh    = (_Float16*)(W + 25600000);   // 12,800,000
  __half*   agg   = (__half*)(W + 38400000);     // 12,800,000
  _Float16* efh   = (_Float16*)(W + 51200000);   // 51,200,000
  int*      srcp  = (int*)(W + 102400000);       // 3,200,000
  int*      dstp  = (int*)(W + 105600000);       // 3,200,000
  float*    cgp   = (float*)(W + 108800000);     // 3,200,000
  int*      counts= (int*)(W + 112000000);       // 200,000
  int*      cursor= (int*)(W + 112200000);       // 200,000
  int*      offs  = (int*)(W + 112400000);       // 200,000
  _Float16* Wm1   = (_Float16*)(W + 112600000);  // 294,912
  _Float16* Wm2   = (_Float16*)(W + 112894912);  // 131,072
  _Float16* Wu1   = (_Float16*)(W + 113025984);  // 262,144
  _Float16* Wu2   = (_Float16*)(W + 113288128);  // 131,072
  _Float16* Wen   = (_Float16*)(W + 113419200);  // 16,384
  float*    Wc    = (float*)(W + 113435584);     // 65,536
  float*    b1f   = (float*)(W + 113501120);     // 2,048
  float*    red   = (float*)(W + 113503168);     // 516

  const int* srcv = eidx;
  const int* dstv = eidx + EE;

  // CSR build + edge permute
  (void)hipMemsetAsync(counts, 0, 400000, stream);  // counts + cursor
  hist_kernel<<<3125, 256, 0, stream>>>(dstv, counts);
  scan_kernel<<<1, 1024, 0, stream>>>(counts, offs);
  slot_kernel<<<3125, 256, 0, stream>>>(srcv, dstv, cong, ef, offs, cursor,
                                        srcp, dstp, cgp, efh);

  // weight prep + encoder
  fold_kernel<<<dim3(33, 4), 128, 0, stream>>>(eew, eeb, mw1, mb1, Wc, b1f);
  prep_msg1<<<dim3(72, 4), 64, 0, stream>>>(mw1, Wc, Wm1);
  prep_w<<<dim3(32, 4), 64, 0, stream>>>(mw2, Wm2, 128, 1);
  prep_w<<<dim3(64, 4), 64, 0, stream>>>(uw1, Wu1, 256, 0);
  prep_w<<<dim3(32, 4), 64, 0, stream>>>(uw2, Wu2, 128, 1);
  prep_w<<<dim3(16, 1), 64, 0, stream>>>(enw, Wen, 64, 0);
  enc_mfma<<<782, 256, 0, stream>>>(nf, Wen, enb, x, xh);

  for (int l = 0; l < 4; l++) {
    (void)hipMemsetAsync(agg, 0, (size_t)NN * 128 * sizeof(__half), stream);
    msg_kernel<<<6250, 256, 0, stream>>>(
        xh, efh, cgp, srcp, dstp,
        Wm1 + (size_t)l * 72 * 512, Wm2 + (size_t)l * 32 * 512,
        mw1 + (size_t)l * 385 * 128 + (size_t)384 * 128,
        b1f + l * 128, mb2 + l * 128, agg);
    upd_kernel<<<782, 256, 0, stream>>>(
        x, xh, (const _Float16*)agg,
        Wu1 + (size_t)l * 64 * 512, Wu2 + (size_t)l * 32 * 512,
        ub1 + l * 128, ub2 + l * 128, lnw + l * 128, lnb + l * 128);
  }

  (void)hipMemsetAsync(red, 0, 129 * sizeof(float), stream);
  reduce_kernel<<<256, 256, 0, stream>>>(x, um, red);
  readout_kernel<<<1, 128, 0, stream>>>(red, xw1, xb1, xw2, xb2,
                                        rw1, rb1, rw2, rb2, rw3, rb3, out);
}

// Round 8
// 979.409 us; speedup vs baseline: 7.0430x; 1.2732x over previous
//
#include <hip/hip_runtime.h>
#include <hip/hip_fp16.h>
#include <math.h>

#define NN 50000
#define EE 800000

typedef _Float16 half8 __attribute__((ext_vector_type(8)));
typedef float floatx4 __attribute__((ext_vector_type(4)));

// ---------------------------------------------------------------------------
// Fold edge-encoder into msg_w1: Wc[l][c][j], b1f[l][j].
// ---------------------------------------------------------------------------
__global__ void fold_kernel(const float* __restrict__ ew, const float* __restrict__ eb,
                            const float* __restrict__ w1, const float* __restrict__ b1,
                            float* __restrict__ Wc, float* __restrict__ b1f) {
  int l = blockIdx.y, c = blockIdx.x, j = threadIdx.x;
  __shared__ float row[128];
  const float* w1l = w1 + (size_t)l * 385 * 128;
  if (c < 32) {
    row[j] = ew[c * 128 + j];
    __syncthreads();
    float acc = 0.f;
    for (int k = 0; k < 128; k++) acc += row[k] * w1l[(256 + k) * 128 + j];
    Wc[((size_t)l * 32 + c) * 128 + j] = acc;
  } else {
    row[j] = eb[j];
    __syncthreads();
    float acc = b1[l * 128 + j];
    for (int k = 0; k < 128; k++) acc += row[k] * w1l[(256 + k) * 128 + j];
    b1f[l * 128 + j] = acc;
  }
}

// ---------------------------------------------------------------------------
// Weight packing into fp16 MFMA B-fragment order. K used as layer stride;
// grid.x = (k_range/32)*8. perm=1 bakes the GEMM2 k-permutation.
// ---------------------------------------------------------------------------
__global__ void prep_w(const float* __restrict__ src, _Float16* __restrict__ dst,
                       int K, int perm) {
  int l = blockIdx.y;
  int lane = threadIdx.x;
  int kc = blockIdx.x >> 3, nt = blockIdx.x & 7;
  int n = nt * 16 + (lane & 15);
  int k0 = kc * 32 + (lane >> 4) * 8;
  const float* s = src + (size_t)l * K * 128;
  _Float16 out[8];
  for (int j = 0; j < 8; j++) {
    int k = k0 + j;
    int ks = perm ? ((k & 7) * 16 + (k >> 3)) : k;
    out[j] = (_Float16)s[(size_t)ks * 128 + n];
  }
  _Float16* d = dst + (((size_t)l * gridDim.x + blockIdx.x) * 64 + lane) * 8;
  *(half8*)d = *(half8*)out;
}

// congestion column (mw1 row 384) -> fp16, k-perm position layout
__global__ void prep_cong(const float* __restrict__ mw1, _Float16* __restrict__ w1cp) {
  int l = blockIdx.x, p = threadIdx.x;
  int col = (p & 7) * 16 + (p >> 3);
  w1cp[l * 128 + p] = (_Float16)mw1[((size_t)l * 385 + 384) * 128 + col];
}

// ---------------------------------------------------------------------------
// CSR build: histogram, scan, slot-scatter + edge pre-permute.
// ---------------------------------------------------------------------------
__global__ void hist_kernel(const int* __restrict__ dstv, int* __restrict__ counts) {
  int e = blockIdx.x * 256 + threadIdx.x;
  if (e < EE) atomicAdd(&counts[dstv[e]], 1);
}

__global__ void scan_kernel(const int* __restrict__ counts, int* __restrict__ offs) {
  __shared__ int ws[16];
  int t = threadIdx.x, lane = t & 63, w = t >> 6;
  int carry = 0;
  for (int chunk = 0; chunk < 49; chunk++) {
    int i = chunk * 1024 + t;
    int v = (i < NN) ? counts[i] : 0;
    int s = v;
    for (int off = 1; off < 64; off <<= 1) {
      int u = __shfl_up(s, off);
      if (lane >= off) s += u;
    }
    if (lane == 63) ws[w] = s;
    __syncthreads();
    if (w == 0) {
      int u = (lane < 16) ? ws[lane] : 0;
      for (int off = 1; off < 16; off <<= 1) {
        int x = __shfl_up(u, off);
        if (lane >= off && lane < 16) u += x;
      }
      if (lane < 16) ws[lane] = u;
    }
    __syncthreads();
    int wbase = (w > 0) ? ws[w - 1] : 0;
    int total = ws[15];
    if (i < NN) offs[i] = carry + wbase + s - v;
    carry += total;
    __syncthreads();
  }
}

__global__ void slot_kernel(const int* __restrict__ srcv, const int* __restrict__ dstv,
                            const float* __restrict__ cong, const float* __restrict__ ef,
                            const int* __restrict__ offs, int* __restrict__ cursor,
                            int* __restrict__ srcp, int* __restrict__ dstp,
                            float* __restrict__ cgp, _Float16* __restrict__ efh) {
  int e = blockIdx.x * 256 + threadIdx.x;
  if (e >= EE) return;
  int d = dstv[e], s = srcv[e];
  int p = offs[d] + atomicAdd(&cursor[d], 1);
  srcp[p] = s;
  dstp[p] = d;
  cgp[p] = cong[s];
  const float* sp = ef + (size_t)e * 32;
  _Float16* dp = efh + (size_t)p * 32;
  for (int i = 0; i < 4; i++) {
    float4 f = *(const float4*)(sp + i * 8);
    float4 g = *(const float4*)(sp + i * 8 + 4);
    half8 v;
    v[0] = (_Float16)f.x; v[1] = (_Float16)f.y; v[2] = (_Float16)f.z; v[3] = (_Float16)f.w;
    v[4] = (_Float16)g.x; v[5] = (_Float16)g.y; v[6] = (_Float16)g.z; v[7] = (_Float16)g.w;
    *(half8*)(dp + i * 8) = v;
  }
}

// ---------------------------------------------------------------------------
// Node encoder via MFMA (writes fp16 xh only).
// ---------------------------------------------------------------------------
__global__ void enc_mfma(const float* __restrict__ nf, const _Float16* __restrict__ Wenc,
                         const float* __restrict__ bn, _Float16* __restrict__ xh) {
  int t = threadIdx.x, wave = t >> 6, lane = t & 63;
  int quad = lane >> 4, l15 = lane & 15;
  long nb0 = (long)blockIdx.x * 64 + wave * 16;
  long rn = nb0 + l15;
  if (rn >= NN) rn = NN - 1;

  floatx4 acc[8] = {};
  for (int kc = 0; kc < 2; kc++) {
    const float* p = nf + rn * 64 + kc * 32 + quad * 8;
    float4 f0 = *(const float4*)p;
    float4 f1 = *(const float4*)(p + 4);
    half8 a;
    a[0] = (_Float16)f0.x; a[1] = (_Float16)f0.y;
    a[2] = (_Float16)f0.z; a[3] = (_Float16)f0.w;
    a[4] = (_Float16)f1.x; a[5] = (_Float16)f1.y;
    a[6] = (_Float16)f1.z; a[7] = (_Float16)f1.w;
    const _Float16* bp = Wenc + (size_t)(kc * 8) * 512 + lane * 8;
    for (int nt = 0; nt < 8; nt++) {
      half8 b = *(const half8*)(bp + nt * 512);
      acc[nt] = __builtin_amdgcn_mfma_f32_16x16x32_f16(a, b, acc[nt], 0, 0, 0);
    }
  }
  float bv[8];
  for (int nt = 0; nt < 8; nt++) bv[nt] = bn[nt * 16 + l15];
  for (int reg = 0; reg < 4; reg++) {
    long n = nb0 + quad * 4 + reg;
    if (n < NN) {
      for (int nt = 0; nt < 8; nt++)
        xh[n * 128 + nt * 16 + l15] = (_Float16)(acc[nt][reg] + bv[nt]);
    }
  }
}

// ---------------------------------------------------------------------------
// Per-layer node precompute: Sh = xh@W1a, Dh = xh@W1b + b1f, both stored in
// k-perm chunk layout (position p = l15*8+nt holds col nt*16+l15).
// block 256 = 4 waves x 16 nodes.
// ---------------------------------------------------------------------------
__global__ __launch_bounds__(256, 3) void sd_kernel(
    const _Float16* __restrict__ xh, const _Float16* __restrict__ WSa,
    const _Float16* __restrict__ WSb, const float* __restrict__ b1f,
    _Float16* __restrict__ Sh, _Float16* __restrict__ Dh) {
  int t = threadIdx.x, wave = t >> 6, lane = t & 63;
  int quad = lane >> 4, l15 = lane & 15;
  long nb0 = (long)blockIdx.x * 64 + wave * 16;
  long rn = nb0 + l15;
  if (rn >= NN) rn = NN - 1;

  floatx4 as_[8] = {}, ad[8] = {};
#pragma unroll
  for (int kc = 0; kc < 4; kc++) {
    half8 a = *(const half8*)(xh + rn * 128 + kc * 32 + quad * 8);
    const _Float16* bpa = WSa + (size_t)(kc * 8) * 512 + lane * 8;
    const _Float16* bpb = WSb + (size_t)(kc * 8) * 512 + lane * 8;
#pragma unroll
    for (int nt = 0; nt < 8; nt++) {
      half8 ba = *(const half8*)(bpa + nt * 512);
      half8 bb = *(const half8*)(bpb + nt * 512);
      as_[nt] = __builtin_amdgcn_mfma_f32_16x16x32_f16(a, ba, as_[nt], 0, 0, 0);
      ad[nt] = __builtin_amdgcn_mfma_f32_16x16x32_f16(a, bb, ad[nt], 0, 0, 0);
    }
  }
  float bbv[8];
  for (int nt = 0; nt < 8; nt++) bbv[nt] = b1f[nt * 16 + l15];
  for (int reg = 0; reg < 4; reg++) {
    long n = nb0 + quad * 4 + reg;
    if (n < NN) {
      half8 hs, hd;
      for (int nt = 0; nt < 8; nt++) {
        hs[nt] = (_Float16)as_[nt][reg];
        hd[nt] = (_Float16)(ad[nt][reg] + bbv[nt]);
      }
      *(half8*)(Sh + n * 128 + l15 * 8) = hs;
      *(half8*)(Dh + n * 128 + l15 * 8) = hd;
    }
  }
}

// ---------------------------------------------------------------------------
// Message kernel v8: GEMM1 replaced by S/D gathers.
// Block = 4 waves, 128 edges. Phase E (M-split): wave computes ef@Wc for its
// 32 edges (16 MFMAs), combines with gathered S[src]/D[dst] chunks + cong
// term, relu, writes h k-perm to LDS. GEMM2 (N-split): 64 MFMAs/wave. Then
// m-tile + segmented reduce + pk-fp16 atomics (as v7).
// ---------------------------------------------------------------------------
__global__ __launch_bounds__(256, 4) void msg_kernel(
    const _Float16* __restrict__ Sh, const _Float16* __restrict__ Dh,
    const _Float16* __restrict__ efh, const float* __restrict__ cgp,
    const int* __restrict__ srcp, const int* __restrict__ dstp,
    const _Float16* __restrict__ Wcp, const _Float16* __restrict__ Wp2,
    const _Float16* __restrict__ w1cp, const float* __restrict__ b2,
    __half* __restrict__ agg) {
  __shared__ __align__(16) _Float16 As[128][136];  // h-tile then m-tile
  __shared__ int s_src[128], s_dst[128];
  __shared__ float s_cg[128];
  int t = threadIdx.x, wave = t >> 6, lane = t & 63;
  int quad = lane >> 4, l15 = lane & 15;
  long eb0 = (long)blockIdx.x * 128;
  int web = wave * 32;
  if (t < 128) {
    s_src[t] = srcp[eb0 + t];
    s_dst[t] = dstp[eb0 + t];
    s_cg[t] = cgp[eb0 + t];
  }
  __syncthreads();

  // congestion weight chunk (perm layout)
  half8 wcl = *(const half8*)(w1cp + l15 * 8);

  // Phase E: per wave, 2 M-tiles of 16 edges
#pragma unroll
  for (int mtl = 0; mtl < 2; mtl++) {
    int rbase = web + mtl * 16;
    // gathers first (in flight during MFMAs)
    half8 sv[4], dv[4];
#pragma unroll
    for (int reg = 0; reg < 4; reg++) {
      int r = rbase + quad * 4 + reg;
      sv[reg] = *(const half8*)(Sh + (size_t)s_src[r] * 128 + l15 * 8);
      dv[reg] = *(const half8*)(Dh + (size_t)s_dst[r] * 128 + l15 * 8);
    }
    half8 a = *(const half8*)(efh + (size_t)(eb0 + rbase + l15) * 32 + quad * 8);
    floatx4 e[8] = {};
#pragma unroll
    for (int nt = 0; nt < 8; nt++) {
      half8 b = *(const half8*)(Wcp + (size_t)nt * 512 + lane * 8);
      e[nt] = __builtin_amdgcn_mfma_f32_16x16x32_f16(a, b, e[nt], 0, 0, 0);
    }
#pragma unroll
    for (int reg = 0; reg < 4; reg++) {
      int r = rbase + quad * 4 + reg;
      float cg = s_cg[r];
      half8 hv;
#pragma unroll
      for (int nt = 0; nt < 8; nt++) {
        float v = (float)sv[reg][nt] + (float)dv[reg][nt] + e[nt][reg] +
                  cg * (float)wcl[nt];
        hv[nt] = (_Float16)fmaxf(v, 0.f);
      }
      *(half8*)&As[r][l15 * 8] = hv;
    }
  }
  __syncthreads();

  // GEMM2 (N-split): wave owns N-tiles {nb, nb+1}
  int nb = wave * 2;
  floatx4 acc2[8][2] = {};
#pragma unroll
  for (int kc = 0; kc < 4; kc++) {
    const _Float16* bp = Wp2 + ((size_t)(kc * 8 + nb)) * 512 + lane * 8;
    half8 b0 = *(const half8*)bp;
    half8 b1v = *(const half8*)(bp + 512);
#pragma unroll
    for (int mt = 0; mt < 8; mt++) {
      half8 a = *(const half8*)&As[mt * 16 + l15][kc * 32 + quad * 8];
      acc2[mt][0] = __builtin_amdgcn_mfma_f32_16x16x32_f16(a, b0, acc2[mt][0], 0, 0, 0);
      acc2[mt][1] = __builtin_amdgcn_mfma_f32_16x16x32_f16(a, b1v, acc2[mt][1], 0, 0, 0);
    }
  }
  __syncthreads();

  // epilogue: bias; pack adjacent columns via lane^1 shuffle; m -> As
  {
    float c0 = b2[nb * 16 + l15], c1 = b2[(nb + 1) * 16 + l15];
#pragma unroll
    for (int mt = 0; mt < 8; mt++)
#pragma unroll
      for (int reg = 0; reg < 4; reg++) {
        int row = mt * 16 + quad * 4 + reg;
#pragma unroll
        for (int ntp = 0; ntp < 2; ntp++) {
          float v = acc2[mt][ntp][reg] + (ntp ? c1 : c0);
          float p = __shfl_xor(v, 1);
          if ((l15 & 1) == 0) {
            __half2 h = __halves2half2(__float2half(v), __float2half(p));
            *(__half2*)&As[row][(nb + ntp) * 16 + l15] = h;
          }
        }
      }
  }
  __syncthreads();

  // segmented reduction over sorted dst runs
  {
    int cp = t & 63;
    int q = t >> 6;
    int r0 = q * 32;
    __half2 vals[32];
#pragma unroll
    for (int i = 0; i < 32; i++) vals[i] = *(__half2*)&As[r0 + i][cp * 2];
    int cur = s_dst[r0];
    float a0 = 0.f, a1 = 0.f;
    for (int i = 0; i < 32; i++) {
      int d = s_dst[r0 + i];
      if (d != cur) {
        unsafeAtomicAdd((__half2*)(agg + (long)cur * 128 + cp * 2),
                        __halves2half2(__float2half(a0), __float2half(a1)));
        a0 = a1 = 0.f;
        cur = d;
      }
      float2 f = __half22float2(vals[i]);
      a0 += f.x;
      a1 += f.y;
    }
    unsafeAtomicAdd((__half2*)(agg + (long)cur * 128 + cp * 2),
                    __halves2half2(__float2half(a0), __float2half(a1)));
  }
}

// ---------------------------------------------------------------------------
// Update + residual + layernorm (MFMA). All state fp16 (xh in-place).
// ---------------------------------------------------------------------------
__global__ __launch_bounds__(256, 3) void upd_kernel(
    _Float16* __restrict__ xh, const _Float16* __restrict__ agg,
    const _Float16* __restrict__ Wp1, const _Float16* __restrict__ Wp2,
    const float* __restrict__ b1, const float* __restrict__ b2,
    const float* __restrict__ g, const float* __restrict__ bb) {
  __shared__ __align__(16) _Float16 hs[4][16][136];
  int t = threadIdx.x, wave = t >> 6, lane = t & 63;
  int quad = lane >> 4, l15 = lane & 15;
  long nb0 = (long)blockIdx.x * 64 + wave * 16;

  floatx4 acc[8] = {};
  {
    long n = nb0 + l15;
    long rn = n < NN ? n : NN - 1;
    for (int kc = 0; kc < 8; kc++) {
      half8 a;
      if (kc < 4) {
        a = *(const half8*)(xh + rn * 128 + kc * 32 + quad * 8);
      } else {
        a = *(const half8*)(agg + rn * 128 + (kc - 4) * 32 + quad * 8);
      }
      const _Float16* bp = Wp1 + (size_t)(kc * 8) * 512 + lane * 8;
      for (int nt = 0; nt < 8; nt++) {
        half8 b = *(const half8*)(bp + nt * 512);
        acc[nt] = __builtin_amdgcn_mfma_f32_16x16x32_f16(a, b, acc[nt], 0, 0, 0);
      }
    }
  }

  float bbv[8];
  for (int nt = 0; nt < 8; nt++) bbv[nt] = b1[nt * 16 + l15];
  for (int reg = 0; reg < 4; reg++) {
    half8 hv;
    for (int nt = 0; nt < 8; nt++)
      hv[nt] = (_Float16)fmaxf(acc[nt][reg] + bbv[nt], 0.f);
    *(half8*)&hs[wave][quad * 4 + reg][l15 * 8] = hv;
  }
  __syncthreads();

  floatx4 acc2[8] = {};
  for (int kc = 0; kc < 4; kc++) {
    half8 a = *(const half8*)&hs[wave][l15][kc * 32 + quad * 8];
    const _Float16* bp = Wp2 + (size_t)(kc * 8) * 512 + lane * 8;
    for (int nt = 0; nt < 8; nt++) {
      half8 b = *(const half8*)(bp + nt * 512);
      acc2[nt] = __builtin_amdgcn_mfma_f32_16x16x32_f16(a, b, acc2[nt], 0, 0, 0);
    }
  }

  float b2v[8], gv[8], bv[8];
  for (int nt = 0; nt < 8; nt++) {
    int col = nt * 16 + l15;
    b2v[nt] = b2[col]; gv[nt] = g[col]; bv[nt] = bb[col];
  }
  for (int reg = 0; reg < 4; reg++) {
    long n = nb0 + quad * 4 + reg;
    bool ok = n < NN;
    long rn = ok ? n : NN - 1;
    float y[8];
    float s = 0.f;
    for (int nt = 0; nt < 8; nt++) {
      y[nt] = (float)xh[rn * 128 + nt * 16 + l15] + acc2[nt][reg] + b2v[nt];
      s += y[nt];
    }
    s += __shfl_xor(s, 1); s += __shfl_xor(s, 2);
    s += __shfl_xor(s, 4); s += __shfl_xor(s, 8);
    float mu = s * (1.f / 128.f);
    float q = 0.f;
    for (int nt = 0; nt < 8; nt++) {
      y[nt] -= mu;
      q += y[nt] * y[nt];
    }
    q += __shfl_xor(q, 1); q += __shfl_xor(q, 2);
    q += __shfl_xor(q, 4); q += __shfl_xor(q, 8);
    float rstd = rsqrtf(q * (1.f / 128.f) + 1e-5f);
    if (ok) {
      for (int nt = 0; nt < 8; nt++) {
        float o = y[nt] * rstd * gv[nt] + bv[nt];
        xh[n * 128 + nt * 16 + l15] = (_Float16)o;
      }
    }
  }
}

// ---------------------------------------------------------------------------
// Global reductions: per-channel sum of xh + unrouted count.
// ---------------------------------------------------------------------------
__global__ void reduce_kernel(const _Float16* __restrict__ xh,
                              const int* __restrict__ umask, float* __restrict__ red) {
  int t = threadIdx.x;
  long base = (long)blockIdx.x * 196;
  int j = t & 127, half = t >> 7;
  float acc = 0.f;
  for (int i = 0; i < 98; i++) {
    long n = base + half + 2L * i;
    if (n < NN) acc += (float)xh[n * 128 + j];
  }
  __shared__ float sr[2][128];
  __shared__ float sm[4];
  sr[half][j] = acc;
  float mv = 0.f;
  {
    long n = base + t;
    if (t < 196 && n < NN) mv = (float)umask[n];
  }
  for (int off = 32; off; off >>= 1) mv += __shfl_xor(mv, off);
  if ((t & 63) == 0) sm[t >> 6] = mv;
  __syncthreads();
  if (t < 128) atomicAdd(&red[t], sr[0][t] + sr[1][t]);
  if (t == 0) atomicAdd(&red[128], sm[0] + sm[1] + sm[2] + sm[3]);
}

// ---------------------------------------------------------------------------
// Readout head.
// ---------------------------------------------------------------------------
__global__ void readout_kernel(const float* __restrict__ red,
                               const float* __restrict__ xw1, const float* __restrict__ xb1,
                               const float* __restrict__ xw2, const float* __restrict__ xb2,
                               const float* __restrict__ rw1, const float* __restrict__ rb1,
                               const float* __restrict__ rw2, const float* __restrict__ rb2,
                               const float* __restrict__ rw3, const float* __restrict__ rb3,
                               float* __restrict__ out) {
  __shared__ float sa[128], sb[128], sc[128];
  int j = threadIdx.x;
  const float inv = 1.f / (float)NN;
  float ge = red[j] * inv;
  float uf = red[128] * inv;
  float u1 = fmaxf(uf * xw1[j] + xb1[j], 0.f);
  sa[j] = u1;
  sb[j] = ge;
  __syncthreads();
  float u2 = xb2[j];
  for (int k = 0; k < 128; k++) u2 += sa[k] * xw2[k * 128 + j];
  sc[j] = u2;
  __syncthreads();
  float h1 = rb1[j];
  for (int k = 0; k < 128; k++) h1 += sb[k] * rw1[k * 128 + j];
  for (int k = 0; k < 128; k++) h1 += sc[k] * rw1[(128 + k) * 128 + j];
  h1 = fmaxf(h1, 0.f);
  __syncthreads();
  sa[j] = h1;
  __syncthreads();
  float h2 = 0.f;
  if (j < 64) {
    h2 = rb2[j];
    for (int k = 0; k < 128; k++) h2 += sa[k] * rw2[k * 64 + j];
    h2 = fmaxf(h2, 0.f);
  }
  __syncthreads();
  if (j < 64) sb[j] = h2;
  __syncthreads();
  if (j == 0) {
    float a = rb3[0];
    for (int k = 0; k < 64; k++) a += sb[k] * rw3[k];
    out[0] = 1.f / (1.f + expf(-a));
  }
}

// ---------------------------------------------------------------------------
extern "C" void kernel_launch(void* const* d_in, const int* in_sizes, int n_in,
                              void* d_out, int out_size, void* d_ws, size_t ws_size,
                              hipStream_t stream) {
  const float* nf   = (const float*)d_in[0];
  const float* ef   = (const float*)d_in[1];
  const float* cong = (const float*)d_in[2];
  const int*   eidx = (const int*)d_in[3];
  const int*   um   = (const int*)d_in[4];
  const float* enw  = (const float*)d_in[5];
  const float* enb  = (const float*)d_in[6];
  const float* eew  = (const float*)d_in[7];
  const float* eeb  = (const float*)d_in[8];
  const float* mw1  = (const float*)d_in[9];
  const float* mb1  = (const float*)d_in[10];
  const float* mw2  = (const float*)d_in[11];
  const float* mb2  = (const float*)d_in[12];
  const float* uw1  = (const float*)d_in[13];
  const float* ub1  = (const float*)d_in[14];
  const float* uw2  = (const float*)d_in[15];
  const float* ub2  = (const float*)d_in[16];
  const float* lnw  = (const float*)d_in[17];
  const float* lnb  = (const float*)d_in[18];
  const float* xw1  = (const float*)d_in[19];
  const float* xb1  = (const float*)d_in[20];
  const float* xw2  = (const float*)d_in[21];
  const float* xb2  = (const float*)d_in[22];
  const float* rw1  = (const float*)d_in[23];
  const float* rb1  = (const float*)d_in[24];
  const float* rw2  = (const float*)d_in[25];
  const float* rb2  = (const float*)d_in[26];
  const float* rw3  = (const float*)d_in[27];
  const float* rb3  = (const float*)d_in[28];
  float* out = (float*)d_out;

  char* W = (char*)d_ws;
  _Float16* xh    = (_Float16*)(W + 0);          // 12,800,000
  __half*   agg   = (__half*)(W + 12800000);     // 12,800,000
  _Float16* efh   = (_Float16*)(W + 25600000);   // 51,200,000
  _Float16* Sh    = (_Float16*)(W + 76800000);   // 12,800,000
  _Float16* Dh    = (_Float16*)(W + 89600000);   // 12,800,000
  int*      srcp  = (int*)(W + 102400000);       // 3,200,000
  int*      dstp  = (int*)(W + 105600000);       // 3,200,000
  float*    cgp   = (float*)(W + 108800000);     // 3,200,000
  int*      counts= (int*)(W + 112000000);       // 200,000
  int*      cursor= (int*)(W + 112200000);       // 200,000
  int*      offs  = (int*)(W + 112400000);       // 200,000
  _Float16* WSa   = (_Float16*)(W + 112600000);  // 131,072
  _Float16* WSb   = (_Float16*)(W + 112731072);  // 131,072
  _Float16* Wcp   = (_Float16*)(W + 112862144);  // 32,768
  _Float16* Wm2   = (_Float16*)(W + 112894912);  // 131,072
  _Float16* Wu1   = (_Float16*)(W + 113025984);  // 262,144
  _Float16* Wu2   = (_Float16*)(W + 113288128);  // 131,072
  _Float16* Wen   = (_Float16*)(W + 113419200);  // 16,384
  float*    Wc    = (float*)(W + 113435584);     // 65,536
  float*    b1f   = (float*)(W + 113501120);     // 2,048
  _Float16* w1cp  = (_Float16*)(W + 113503168);  // 1,024
  float*    red   = (float*)(W + 113504192);     // 516

  const int* srcv = eidx;
  const int* dstv = eidx + EE;

  // CSR build + edge permute
  (void)hipMemsetAsync(counts, 0, 400000, stream);  // counts + cursor
  hist_kernel<<<3125, 256, 0, stream>>>(dstv, counts);
  scan_kernel<<<1, 1024, 0, stream>>>(counts, offs);
  slot_kernel<<<3125, 256, 0, stream>>>(srcv, dstv, cong, ef, offs, cursor,
                                        srcp, dstp, cgp, efh);

  // weight prep + encoder
  fold_kernel<<<dim3(33, 4), 128, 0, stream>>>(eew, eeb, mw1, mb1, Wc, b1f);
  prep_w<<<dim3(8, 4), 64, 0, stream>>>(Wc, Wcp, 32, 0);
  prep_w<<<dim3(32, 4), 64, 0, stream>>>(mw1, WSa, 385, 0);
  prep_w<<<dim3(32, 4), 64, 0, stream>>>(mw1 + 128 * 128, WSb, 385, 0);
  prep_w<<<dim3(32, 4), 64, 0, stream>>>(mw2, Wm2, 128, 1);
  prep_w<<<dim3(64, 4), 64, 0, stream>>>(uw1, Wu1, 256, 0);
  prep_w<<<dim3(32, 4), 64, 0, stream>>>(uw2, Wu2, 128, 1);
  prep_w<<<dim3(16, 1), 64, 0, stream>>>(enw, Wen, 64, 0);
  prep_cong<<<4, 128, 0, stream>>>(mw1, w1cp);
  enc_mfma<<<782, 256, 0, stream>>>(nf, Wen, enb, xh);

  for (int l = 0; l < 4; l++) {
    sd_kernel<<<782, 256, 0, stream>>>(
        xh, WSa + (size_t)l * 32 * 512, WSb + (size_t)l * 32 * 512,
        b1f + l * 128, Sh, Dh);
    (void)hipMemsetAsync(agg, 0, (size_t)NN * 128 * sizeof(__half), stream);
    msg_kernel<<<6250, 256, 0, stream>>>(
        Sh, Dh, efh, cgp, srcp, dstp,
        Wcp + (size_t)l * 8 * 512, Wm2 + (size_t)l * 32 * 512,
        w1cp + l * 128, mb2 + l * 128, agg);
    upd_kernel<<<782, 256, 0, stream>>>(
        xh, (const _Float16*)agg,
        Wu1 + (size_t)l * 64 * 512, Wu2 + (size_t)l * 32 * 512,
        ub1 + l * 128, ub2 + l * 128, lnw + l * 128, lnb + l * 128);
  }

  (void)hipMemsetAsync(red, 0, 129 * sizeof(float), stream);
  reduce_kernel<<<256, 256, 0, stream>>>(xh, um, red);
  readout_kernel<<<1, 128, 0, stream>>>(red, xw1, xb1, xw2, xb2,
                                        rw1, rb1, rw2, rb2, rw3, rb3, out);
}